// Round 4
// baseline (2922.792 us; speedup 1.0000x reference)
//
#include <hip/hip_runtime.h>
#include <hip/hip_bf16.h>
#include <math.h>

typedef __hip_bfloat16 bf16;

#define B_ 2
#define S_ 1025
#define D_ 1024
#define H_ 16
#define HD_ 64
#define P_ 1024
#define K_ 32

static constexpr float TEMP_ = 0.1f;
static constexpr float SCALE_ = 0.125f;   // HD^-0.5
static constexpr float EPS_LN_ = 1e-5f;

__device__ __forceinline__ float bfraw2f(unsigned short u) {
  unsigned int t = ((unsigned int)u) << 16;
  float f;
  __builtin_memcpy(&f, &t, 4);
  return f;
}

// dtype-flagged buffer access (bf: 1 = bf16, 0 = f32)
__device__ __forceinline__ float getb(const void* p, long long i, int bf) {
  if (bf) return __bfloat162float(((const bf16*)p)[i]);
  return ((const float*)p)[i];
}
__device__ __forceinline__ void setb(void* p, long long i, int bf, float v) {
  if (bf) ((bf16*)p)[i] = __float2bfloat16(v);
  else ((float*)p)[i] = v;
}
__device__ __forceinline__ void load4b(const void* p, long long i, int bf, float v[4]) {
  if (bf) {
    ushort4 t = *reinterpret_cast<const ushort4*>((const bf16*)p + i);
    v[0] = bfraw2f(t.x); v[1] = bfraw2f(t.y); v[2] = bfraw2f(t.z); v[3] = bfraw2f(t.w);
  } else {
    float4 t = *reinterpret_cast<const float4*>((const float*)p + i);
    v[0] = t.x; v[1] = t.y; v[2] = t.z; v[3] = t.w;
  }
}

__device__ __forceinline__ float gelu_f(float x) {
  return 0.5f * x * (1.0f + erff(x * 0.70710678118654752f));
}

// ---- dtype probe: norm1_w is all-ones. fp32 1.0 = 0x3F800000 (halves differ),
// bf16 pair = 0x3F803F80 (halves equal). r1-vs-r2 behavior proved this picks f32. ----
__global__ void probe_kernel(const unsigned int* __restrict__ w1, int* __restrict__ flag) {
  unsigned int u = w1[0];
  *flag = ((u >> 16) == (u & 0xFFFFu)) ? 1 : 0;
}

// ---- block reductions (blockDim.x == 256 assumed) ----
__device__ __forceinline__ float block_sum256(float v, float* red4) {
  for (int off = 32; off > 0; off >>= 1) v += __shfl_down(v, off);
  if ((threadIdx.x & 63) == 0) red4[threadIdx.x >> 6] = v;
  __syncthreads();
  float r = red4[0] + red4[1] + red4[2] + red4[3];
  __syncthreads();
  return r;
}
__device__ __forceinline__ float block_max256(float v, float* red4) {
  for (int off = 32; off > 0; off >>= 1) v = fmaxf(v, __shfl_down(v, off));
  if ((threadIdx.x & 63) == 0) red4[threadIdx.x >> 6] = v;
  __syncthreads();
  float r = fmaxf(fmaxf(red4[0], red4[1]), fmaxf(red4[2], red4[3]));
  __syncthreads();
  return r;
}

// ---- LayerNorm: one block (256 thr) per row of D=1024 ----
// x_md/o_md: 0=f32, 1=bf16, 2=follow probe. w/b always follow probe.
__global__ __launch_bounds__(256) void ln_kernel(const void* __restrict__ x, int x_md,
                                                 const void* __restrict__ w,
                                                 const void* __restrict__ b,
                                                 const int* __restrict__ flagp,
                                                 void* __restrict__ out, int o_md) {
  __shared__ float red4[4];
  const int pf = flagp[0];
  const int xm = (x_md == 2) ? pf : x_md;
  const int row = blockIdx.x;
  const long long base = (long long)row * D_;
  float v[4];
  float s = 0.f, ss = 0.f;
#pragma unroll
  for (int u = 0; u < 4; ++u) {
    int d = threadIdx.x + u * 256;
    float f = getb(x, base + d, xm);
    v[u] = f;
    s += f;
    ss += f * f;
  }
  float tot = block_sum256(s, red4);
  float tot2 = block_sum256(ss, red4);
  float mean = tot * (1.0f / D_);
  float var = tot2 * (1.0f / D_) - mean * mean;
  float rstd = rsqrtf(var + EPS_LN_);
#pragma unroll
  for (int u = 0; u < 4; ++u) {
    int d = threadIdx.x + u * 256;
    setb(out, base + d, o_md, (v[u] - mean) * rstd * getb(w, d, pf) + getb(b, d, pf));
  }
}

// ---- L2 normalize rows in-place (D=1024), 256 thr/row ----
__global__ __launch_bounds__(256) void l2norm_kernel(void* __restrict__ x, int md) {
  __shared__ float red4[4];
  const int row = blockIdx.x;
  const long long base = (long long)row * D_;
  float v[4];
  float ss = 0.f;
#pragma unroll
  for (int u = 0; u < 4; ++u) {
    int d = threadIdx.x + u * 256;
    v[u] = getb(x, base + d, md);
    ss += v[u] * v[u];
  }
  float tot = block_sum256(ss, red4);
  float inv = 1.0f / fmaxf(sqrtf(tot), 1e-12f);
#pragma unroll
  for (int u = 0; u < 4; ++u) {
    int d = threadIdx.x + u * 256;
    setb(x, base + d, md, v[u] * inv);
  }
}

// ---- Generic GEMM: out[n,m] = sum_k A[n,k] * W[m*w_stride+k] (+ epilogue) ----
// MODE 0: (+bias), store st_md
// MODE 1: (+bias) + ep[row,m] (ep_md), store st_md      (proj / fc2 first half)
// MODE 2: gelu((+bias)), store st_md                    (fc1 halves)
// MODE 3: (+bias) + ep f32, store f32 to outB           (fc2 second half -> d_out)
// MODE 4: + ep pos_bias[p,m] (ep_md), diag(p==m)=-1e9, store st_md (scores)
template <int MODE>
__global__ __launch_bounds__(256) void sgemm_kernel(
    const void* __restrict__ A, int a_md, long long a_off,
    const void* __restrict__ W, int w_md, long long w_off, int w_stride,
    const void* __restrict__ bias, int add_bias, int bias_off,
    const void* __restrict__ ep, int ep_md,
    void* __restrict__ outF, int st_md, void* __restrict__ outB,
    const int* __restrict__ flagp,
    int N, int M, int Kd, int rpb, long long a_bs, long long w_bs) {
  __shared__ float sA[128][9];
  __shared__ float sW[128][9];
  const int pf = flagp[0];
  const int am = (a_md == 2) ? pf : a_md;
  const int wm = (w_md == 2) ? pf : w_md;
  const int em = (ep_md == 2) ? pf : ep_md;
  const int tid = threadIdx.x;
  const int tx = tid & 15, ty = tid >> 4;
  const int row0 = blockIdx.y * 128;
  const int col0 = blockIdx.x * 128;
  const int batch = row0 / rpb;
  const int lrow = tid >> 1;       // 0..127
  const int lk = (tid & 1) * 4;    // 0 or 4
  const long long abase = a_off + (long long)batch * a_bs +
                          (long long)(row0 - batch * rpb) * Kd;
  const long long wbase = w_off + (long long)batch * w_bs;
  float acc[8][8] = {};
  for (int k0 = 0; k0 < Kd; k0 += 8) {
    float av[4], wv[4];
    if (row0 + lrow < N)
      load4b(A, abase + (long long)lrow * Kd + k0 + lk, am, av);
    else
      av[0] = av[1] = av[2] = av[3] = 0.f;
    load4b(W, wbase + (long long)(col0 + lrow) * w_stride + k0 + lk, wm, wv);
#pragma unroll
    for (int u = 0; u < 4; ++u) {
      sA[lrow][lk + u] = av[u];
      sW[lrow][lk + u] = wv[u];
    }
    __syncthreads();
#pragma unroll
    for (int kk = 0; kk < 8; ++kk) {
      float a[8], w[8];
#pragma unroll
      for (int i = 0; i < 8; ++i) a[i] = sA[ty + 16 * i][kk];
#pragma unroll
      for (int j = 0; j < 8; ++j) w[j] = sW[tx + 16 * j][kk];
#pragma unroll
      for (int i = 0; i < 8; ++i)
#pragma unroll
        for (int j = 0; j < 8; ++j) acc[i][j] += a[i] * w[j];
    }
    __syncthreads();
  }
#pragma unroll
  for (int i = 0; i < 8; ++i) {
    int grow = row0 + ty + 16 * i;
    if (grow >= N) continue;
    long long rowoff = (long long)grow * M;
#pragma unroll
    for (int j = 0; j < 8; ++j) {
      int gcol = col0 + tx + 16 * j;
      float v = acc[i][j];
      if (add_bias) v += getb(bias, bias_off + gcol, pf);
      if (MODE == 1) v += getb(ep, rowoff + gcol, em);
      if (MODE == 2) v = gelu_f(v);
      if (MODE == 4) {
        int p = grow - batch * rpb;
        v += getb(ep, (long long)p * M + gcol, em);
        if (p == gcol) v = -1e9f;
      }
      if (MODE == 3) {
        float r = ((const float*)ep)[rowoff + gcol];
        ((float*)outB)[rowoff + gcol] = v + r;   // d_out is float32 (reference output dtype)
      } else {
        setb(outF, rowoff + gcol, st_md, v);
      }
    }
  }
}

// ---- top-32 per row of scores (P=1024), one block (256 thr) per row ----
__global__ __launch_bounds__(256) void topk_kernel(const float* __restrict__ scores,
                                                   int* __restrict__ routes,
                                                   float* __restrict__ logw) {
  __shared__ float sv[1024];
  __shared__ float rv[256];
  __shared__ int ri[256];
  __shared__ float selv[K_];
  __shared__ int seli[K_];
  const int row = blockIdx.x;
  const int tid = threadIdx.x;
  const float* sr = scores + (long long)row * P_;
#pragma unroll
  for (int u = 0; u < 4; ++u) sv[tid + u * 256] = sr[tid + u * 256];
  __syncthreads();
  for (int t = 0; t < K_; ++t) {
    float bv = -3.0e38f;
    int bi = 0;
    const int base = tid * 4;
#pragma unroll
    for (int u = 0; u < 4; ++u) {
      float v = sv[base + u];
      if (v > bv) { bv = v; bi = base + u; }
    }
    rv[tid] = bv;
    ri[tid] = bi;
    __syncthreads();
    for (int sft = 128; sft > 0; sft >>= 1) {
      if (tid < sft) {
        float ov = rv[tid + sft];
        int oi = ri[tid + sft];
        if (ov > rv[tid] || (ov == rv[tid] && oi < ri[tid])) {
          rv[tid] = ov;
          ri[tid] = oi;
        }
      }
      __syncthreads();
    }
    if (tid == 0) {
      selv[t] = rv[0];
      seli[t] = ri[0];
      sv[ri[0]] = -3.0e38f;
    }
    __syncthreads();
  }
  if (tid == 0) {
    const float m = selv[0] / TEMP_;  // first pick is the max
    float sum = 0.f;
    for (int k = 0; k < K_; ++k) sum += expf(selv[k] / TEMP_ - m);
    const float lse = logf(sum);
    for (int k = 0; k < K_; ++k) {
      float lw = selv[k] / TEMP_ - m - lse;
      logw[(long long)row * K_ + k] = fmaxf(lw, -10.0f);
      routes[(long long)row * K_ + k] = seli[k];
    }
  }
}

// ---- cls-token attention: one block (256 thr) per (b,h) ----
__global__ __launch_bounds__(256) void attn_cls_kernel(const void* __restrict__ qkv, int qm,
                                                       void* __restrict__ out, int om) {
  __shared__ float q[HD_];
  __shared__ float lg[S_];
  __shared__ float redm[4];
  __shared__ float reds[4];
  const int b = blockIdx.x >> 4;
  const int h = blockIdx.x & 15;
  const int tid = threadIdx.x;
  const long long base = (long long)b * S_ * 3072;
  if (tid < HD_) q[tid] = getb(qkv, base + h * HD_ + tid, qm);
  __syncthreads();
  float lmax = -3.0e38f;
  for (int s = tid; s < S_; s += 256) {
    const long long kb = base + (long long)s * 3072 + 1024 + h * HD_;
    float d = 0.f;
#pragma unroll
    for (int e = 0; e < HD_; ++e) d += q[e] * getb(qkv, kb + e, qm);
    d *= SCALE_;
    lg[s] = d;
    lmax = fmaxf(lmax, d);
  }
  const float m = block_max256(lmax, redm);
  float sum = 0.f;
  for (int s = tid; s < S_; s += 256) {
    float e = expf(lg[s] - m);
    lg[s] = e;
    sum += e;
  }
  const float tot = block_sum256(sum, reds);
  if (tid < HD_) {
    float acc = 0.f;
    for (int s = 0; s < S_; ++s)
      acc += lg[s] * getb(qkv, base + (long long)s * 3072 + 2048 + h * HD_ + tid, qm);
    setb(out, (long long)(b * S_) * D_ + h * HD_ + tid, om, acc / tot);
  }
}

// ---- routed patch attention: one block (64 thr) per (b,p,h) ----
__global__ __launch_bounds__(64) void attn_patch_kernel(const void* __restrict__ qkv, int qm,
                                                        const int* __restrict__ routes,
                                                        const float* __restrict__ logw,
                                                        void* __restrict__ out, int om) {
  __shared__ float q[HD_];
  __shared__ float lgs[K_];
  __shared__ float wk[K_];
  __shared__ int sidx[K_];
  const int bid = blockIdx.x;
  const int h = bid & 15;
  const int p = (bid >> 4) & (P_ - 1);
  const int b = bid >> 14;
  const int tid = threadIdx.x;
  const long long base = (long long)b * S_ * 3072;
  q[tid] = getb(qkv, base + (long long)(1 + p) * 3072 + h * HD_ + tid, qm);
  __syncthreads();
  if (tid < K_) {
    const long long ro = ((long long)(b * P_ + p)) * K_ + tid;
    const int r = routes[ro];
    sidx[tid] = r;
    const long long kb = base + (long long)(1 + r) * 3072 + 1024 + h * HD_;
    float d = 0.f;
#pragma unroll
    for (int e = 0; e < HD_; ++e) d += q[e] * getb(qkv, kb + e, qm);
    lgs[tid] = d * SCALE_ + logw[ro];
  }
  __syncthreads();
  if (tid == 0) {
    float m = -3.0e38f;
    for (int k = 0; k < K_; ++k) m = fmaxf(m, lgs[k]);
    float s = 0.f;
    for (int k = 0; k < K_; ++k) {
      wk[k] = expf(lgs[k] - m);
      s += wk[k];
    }
    const float inv = 1.0f / s;
    for (int k = 0; k < K_; ++k) wk[k] *= inv;
  }
  __syncthreads();
  float acc = 0.f;
  for (int k = 0; k < K_; ++k)
    acc += wk[k] * getb(qkv, base + (long long)(1 + sidx[k]) * 3072 + 2048 + h * HD_ + tid, qm);
  setb(out, ((long long)(b * S_) + 1 + p) * D_ + h * HD_ + tid, om, acc);
}

extern "C" void kernel_launch(void* const* d_in, const int* in_sizes, int n_in,
                              void* d_out, int out_size, void* d_ws, size_t ws_size,
                              hipStream_t stream) {
  const void* x      = d_in[0];
  const void* n1w    = d_in[1];
  const void* n1b    = d_in[2];
  const void* rq_w   = d_in[3];
  const void* rq_b   = d_in[4];
  const void* rk_w   = d_in[5];
  const void* rk_b   = d_in[6];
  const void* pos    = d_in[7];
  const void* qkv_w  = d_in[8];
  const void* qkv_b  = d_in[9];
  const void* proj_w = d_in[10];
  const void* proj_b = d_in[11];
  const void* n2w    = d_in[12];
  const void* n2b    = d_in[13];
  const void* fc1_w  = d_in[14];
  const void* fc1_b  = d_in[15];
  const void* fc2_w  = d_in[16];
  const void* fc2_b  = d_in[17];

  // ---- ws_size-adaptive layout ----
  // Tier 0 (f32 intermediates) needs 50,905,344 B; Tier 1 (bf16) needs 29,913,344 B.
  const int tier = (ws_size >= 50905344ULL) ? 0 : 1;
  const int md = tier ? 1 : 0;        // intermediate dtype: 0=f32, 1=bf16
  const int xn_md = md, qk_md = md, qkv_md = md, h_md = md, at_md = md;
  const size_t s_xn  = tier ? 4198400ULL : 8396800ULL;   // xnorm (2050x1024)
  const size_t s_q   = 8396800ULL;                       // max(q_r, x1 f32)
  const size_t s_k   = tier ? 4198400ULL : 8396800ULL;   // max(k_r, attn)
  const size_t s_big = tier ? 12595200ULL : 25190400ULL; // max(scores f32, qkv, hbuf_half)

  char* mem   = (char*)d_ws;
  int*  flag   = (int*)mem;                 // 256 B reserved
  int*  routes = (int*)(mem + 256);         // 262,144 B
  float* logw  = (float*)(mem + 262400);    // 262,144 B
  char* p_xn  = mem + 524544;
  char* p_q   = p_xn + s_xn;
  char* p_k   = p_q + s_q;
  char* p_big = p_k + s_k;
  void*  xnorm  = p_xn;                 // live: ln1..qkv, then ln2..fc1b
  void*  qr     = p_q;                  // live: rq..scores
  float* x1     = (float*)p_q;          // live: proj..fc2b (f32 always)
  void*  kr     = p_k;                  // live: rk..scores
  void*  attn   = p_k;                  // live: attn..proj
  float* scores = (float*)p_big;        // live: scores..topk (f32 always)
  void*  qkvb   = p_big;                // live: qkv..attn
  void*  hbuf   = p_big;                // live: fc1a..fc2a / fc1b..fc2b (2050x2048)

  // 0. dtype probe (norm1_w is all-ones)
  probe_kernel<<<1, 1, 0, stream>>>((const unsigned int*)n1w, flag);

  // 1. LayerNorm1: x -> xnorm
  ln_kernel<<<B_ * S_, 256, 0, stream>>>(x, 2, n1w, n1b, flag, xnorm, xn_md);

  // 2. q_lin / k_lin on patch tokens (skip token 0): N=2048, M=1024, K=1024
  dim3 gRQ(8, 16);
  sgemm_kernel<0><<<gRQ, 256, 0, stream>>>(xnorm, xn_md, 1024LL, rq_w, 2, 0LL, 1024,
      rq_b, 1, 0, nullptr, 0, qr, qk_md, nullptr, flag,
      2048, 1024, 1024, 1024, (long long)S_ * D_, 0LL);
  sgemm_kernel<0><<<gRQ, 256, 0, stream>>>(xnorm, xn_md, 1024LL, rk_w, 2, 0LL, 1024,
      rk_b, 1, 0, nullptr, 0, kr, qk_md, nullptr, flag,
      2048, 1024, 1024, 1024, (long long)S_ * D_, 0LL);
  l2norm_kernel<<<2048, 256, 0, stream>>>(qr, qk_md);
  l2norm_kernel<<<2048, 256, 0, stream>>>(kr, qk_md);

  // 3. scores[b,p,q] = q_r . k_r + pos_bias, diag=-1e9
  sgemm_kernel<4><<<gRQ, 256, 0, stream>>>(qr, qk_md, 0LL, kr, qk_md, 0LL, 1024,
      nullptr, 0, 0, pos, 2, scores, 0, nullptr, flag,
      2048, 1024, 1024, 1024, (long long)P_ * D_, (long long)P_ * D_);

  // 4. top-32 routing + log route weights
  topk_kernel<<<2048, 256, 0, stream>>>(scores, routes, logw);

  // 5. qkv: N=2050, M=3072, K=1024
  sgemm_kernel<0><<<dim3(24, 17), 256, 0, stream>>>(xnorm, xn_md, 0LL, qkv_w, 2, 0LL, 1024,
      qkv_b, 1, 0, nullptr, 0, qkvb, qkv_md, nullptr, flag,
      2050, 3072, 1024, 2050, 0LL, 0LL);

  // 6. attention -> attn (BxSxD)
  attn_cls_kernel<<<B_ * H_, 256, 0, stream>>>(qkvb, qkv_md, attn, at_md);
  attn_patch_kernel<<<B_ * P_ * H_, 64, 0, stream>>>(qkvb, qkv_md, routes, logw, attn, at_md);

  // 7. proj + residual(x): x1 = x + attn @ proj_w^T + proj_b
  sgemm_kernel<1><<<dim3(8, 17), 256, 0, stream>>>(attn, at_md, 0LL, proj_w, 2, 0LL, 1024,
      proj_b, 1, 0, x, 2, x1, 0, nullptr, flag,
      2050, 1024, 1024, 2050, 0LL, 0LL);

  // 8. LayerNorm2: x1 -> xnorm (reuse)
  ln_kernel<<<B_ * S_, 256, 0, stream>>>(x1, 0, n2w, n2b, flag, xnorm, xn_md);

  // 9a. fc1 first half (cols 0..2047) + gelu -> hbuf
  sgemm_kernel<2><<<dim3(16, 17), 256, 0, stream>>>(xnorm, xn_md, 0LL, fc1_w, 2, 0LL, 1024,
      fc1_b, 1, 0, nullptr, 0, hbuf, h_md, nullptr, flag,
      2050, 2048, 1024, 2050, 0LL, 0LL);
  // 9b. fc2 first half: x1 += hbuf @ fc2_w[:, :2048]^T + fc2_b
  sgemm_kernel<1><<<dim3(8, 17), 256, 0, stream>>>(hbuf, h_md, 0LL, fc2_w, 2, 0LL, 4096,
      fc2_b, 1, 0, x1, 0, x1, 0, nullptr, flag,
      2050, 1024, 2048, 2050, 0LL, 0LL);
  // 9c. fc1 second half (cols 2048..4095) + gelu -> hbuf (reuse)
  sgemm_kernel<2><<<dim3(16, 17), 256, 0, stream>>>(xnorm, xn_md, 0LL, fc1_w, 2,
      (long long)2048 * 1024, 1024, fc1_b, 1, 2048, nullptr, 0, hbuf, h_md, nullptr, flag,
      2050, 2048, 1024, 2050, 0LL, 0LL);
  // 9d. fc2 second half + x1 -> d_out (f32): N=2050, M=1024, K=2048
  sgemm_kernel<3><<<dim3(8, 17), 256, 0, stream>>>(hbuf, h_md, 0LL, fc2_w, 2, 2048LL, 4096,
      nullptr, 0, 0, x1, 0, nullptr, 0, d_out, flag,
      2050, 1024, 2048, 2050, 0LL, 0LL);
}

// Round 5
// 626.603 us; speedup vs baseline: 4.6645x; 4.6645x over previous
//
#include <hip/hip_runtime.h>
#include <hip/hip_bf16.h>
#include <math.h>

typedef unsigned short u16;
typedef __attribute__((ext_vector_type(8))) short short8;
typedef __attribute__((ext_vector_type(4))) float f32x4;

#define B_ 2
#define S_ 1025
#define D_ 1024
#define H_ 16
#define HD_ 64
#define P_ 1024
#define K_ 32

static constexpr float TEMP_ = 0.1f;
static constexpr float SCALE_ = 0.125f;
static constexpr float EPS_LN_ = 1e-5f;

__device__ __forceinline__ float bf2f(u16 u) {
  unsigned int t = ((unsigned int)u) << 16;
  float f;
  __builtin_memcpy(&f, &t, 4);
  return f;
}
__device__ __forceinline__ u16 f2bf(float f) {
  __hip_bfloat16 h = __float2bfloat16(f);
  u16 u;
  __builtin_memcpy(&u, &h, 2);
  return u;
}
__device__ __forceinline__ float gelu_f(float x) {
  return 0.5f * x * (1.0f + erff(x * 0.70710678118654752f));
}

// async global->LDS, 16B per lane. LDS dest must be wave-uniform base + lane*16.
typedef __attribute__((address_space(1))) const unsigned int gas_u32;
typedef __attribute__((address_space(3))) unsigned int las_u32;
__device__ __forceinline__ void g2l16(const void* g, void* l) {
  __builtin_amdgcn_global_load_lds((gas_u32*)g, (las_u32*)l, 16, 0, 0);
}

// ---- weight convert f32 -> bf16, [M,Kd] row-major dst; src row stride sstr, offset soff
__global__ __launch_bounds__(256) void conv_kernel(const float* __restrict__ src,
                                                   long long soff, int sstr,
                                                   u16* __restrict__ dst,
                                                   int total, int kshift) {
  int e = (blockIdx.x * 256 + threadIdx.x) * 4;
  if (e >= total) return;
  int m = e >> kshift;
  int k = e - (m << kshift);
  float4 t = *reinterpret_cast<const float4*>(src + soff + (long long)m * sstr + k);
  ushort4 o;
  o.x = f2bf(t.x); o.y = f2bf(t.y); o.z = f2bf(t.z); o.w = f2bf(t.w);
  *reinterpret_cast<ushort4*>(dst + e) = o;
}

// ---- block reductions (256 threads) ----
__device__ __forceinline__ float block_sum256(float v, float* red4) {
  for (int off = 32; off > 0; off >>= 1) v += __shfl_down(v, off);
  if ((threadIdx.x & 63) == 0) red4[threadIdx.x >> 6] = v;
  __syncthreads();
  float r = red4[0] + red4[1] + red4[2] + red4[3];
  __syncthreads();
  return r;
}
__device__ __forceinline__ float block_max256(float v, float* red4) {
  for (int off = 32; off > 0; off >>= 1) v = fmaxf(v, __shfl_down(v, off));
  if ((threadIdx.x & 63) == 0) red4[threadIdx.x >> 6] = v;
  __syncthreads();
  float r = fmaxf(fmaxf(red4[0], red4[1]), fmaxf(red4[2], red4[3]));
  __syncthreads();
  return r;
}

// ---- LayerNorm f32 in -> bf16 out, one block per row ----
__global__ __launch_bounds__(256) void ln_kernel(const float* __restrict__ x,
                                                 const float* __restrict__ w,
                                                 const float* __restrict__ b,
                                                 u16* __restrict__ out) {
  __shared__ float red4[4];
  const long long base = (long long)blockIdx.x * D_;
  float v[4];
  float s = 0.f, ss = 0.f;
#pragma unroll
  for (int u = 0; u < 4; ++u) {
    int d = threadIdx.x + u * 256;
    float f = x[base + d];
    v[u] = f; s += f; ss += f * f;
  }
  float tot = block_sum256(s, red4);
  float tot2 = block_sum256(ss, red4);
  float mean = tot * (1.0f / D_);
  float var = tot2 * (1.0f / D_) - mean * mean;
  float rstd = rsqrtf(var + EPS_LN_);
#pragma unroll
  for (int u = 0; u < 4; ++u) {
    int d = threadIdx.x + u * 256;
    out[base + d] = f2bf((v[u] - mean) * rstd * w[d] + b[d]);
  }
}

// ---- L2 normalize rows in-place (bf16) ----
__global__ __launch_bounds__(256) void l2norm_kernel(u16* __restrict__ x) {
  __shared__ float red4[4];
  const long long base = (long long)blockIdx.x * D_;
  float v[4];
  float ss = 0.f;
#pragma unroll
  for (int u = 0; u < 4; ++u) {
    int d = threadIdx.x + u * 256;
    v[u] = bf2f(x[base + d]);
    ss += v[u] * v[u];
  }
  float tot = block_sum256(ss, red4);
  float inv = 1.0f / fmaxf(sqrtf(tot), 1e-12f);
#pragma unroll
  for (int u = 0; u < 4; ++u) {
    int d = threadIdx.x + u * 256;
    x[base + d] = f2bf(v[u] * inv);
  }
}

// ---- MFMA GEMM: out[n,m] = sum_k A[n,k]*W[m,k], 128x128 tile, bf16 inputs ----
// MODE 0: RQK   : m<1024 -> outU=bf16(v+bias[m]); else outU2=bf16(v+bias2[m-1024])
// MODE 1: SCORES: v += ep(pos)[p*1024+m]; diag -1e9; outF f32
// MODE 2: BIAS  : outU = bf16(v + bias[bias_off+m])
// MODE 3: GELU  : outU = bf16(gelu(v + bias[bias_off+m]))
// MODE 4: RES   : outF = v + (bias?bias[m]:0) + ep[n*M+m]   (f32 out)
template <int MODE>
__global__ __launch_bounds__(256, 2) void mfma_gemm(
    const u16* __restrict__ A, long long a_off, const u16* __restrict__ W,
    int N, int M, int Kd, int rpb, long long a_bs, long long w_bs,
    const float* __restrict__ bias, const float* __restrict__ bias2, int bias_off,
    const float* __restrict__ ep,
    u16* __restrict__ outU, u16* __restrict__ outU2, float* __restrict__ outF) {
  __shared__ u16 sA[128 * 32];
  __shared__ u16 sW[128 * 32];
  const int tid = threadIdx.x;
  const int lane = tid & 63;
  const int q4 = lane >> 4;
  const int r16 = lane & 15;
  const int wave = tid >> 6;
  const int wr = (wave >> 1) * 64;
  const int wc = (wave & 1) * 64;
  const int row0 = blockIdx.y * 128;
  const int col0 = blockIdx.x * 128;
  const int batch = row0 / rpb;
  const u16* Ab = A + a_off + (long long)batch * a_bs +
                  (long long)(row0 - batch * rpb) * Kd;
  const u16* Wb = W + (long long)batch * w_bs + (long long)col0 * Kd;
  // staging: chunk id = q*256+tid; row=id>>2 (0..127), k-sub=(id&3)*8; LDS off=id*16B
  const int srow = tid >> 2;
  const int sko = (tid & 3) * 8;
  const int rmax = N - 1 - row0;  // clamp edge rows (garbage rows unused in epilogue)
  const long long aoff0 = (long long)min(srow, rmax) * Kd + sko;
  const long long aoff1 = (long long)min(srow + 64, rmax) * Kd + sko;
  const long long woff0 = (long long)srow * Kd + sko;
  const long long woff1 = (long long)(srow + 64) * Kd + sko;
  f32x4 acc[4][4] = {};
  for (int k0 = 0; k0 < Kd; k0 += 32) {
    g2l16(Ab + aoff0 + k0, &sA[tid * 8]);
    g2l16(Ab + aoff1 + k0, &sA[2048 + tid * 8]);
    g2l16(Wb + woff0 + k0, &sW[tid * 8]);
    g2l16(Wb + woff1 + k0, &sW[2048 + tid * 8]);
    __builtin_amdgcn_s_waitcnt(0);
    __syncthreads();
    short8 a[4], b[4];
#pragma unroll
    for (int i = 0; i < 4; ++i)
      a[i] = *reinterpret_cast<const short8*>(&sA[(wr + i * 16 + r16) * 32 + q4 * 8]);
#pragma unroll
    for (int j = 0; j < 4; ++j)
      b[j] = *reinterpret_cast<const short8*>(&sW[(wc + j * 16 + r16) * 32 + q4 * 8]);
#pragma unroll
    for (int i = 0; i < 4; ++i)
#pragma unroll
      for (int j = 0; j < 4; ++j)
        acc[i][j] = __builtin_amdgcn_mfma_f32_16x16x32_bf16(a[i], b[j], acc[i][j], 0, 0, 0);
    __syncthreads();
  }
  // epilogue: n = row0+wr+i*16+q4*4+reg ; m = col0+wc+j*16+r16
#pragma unroll
  for (int i = 0; i < 4; ++i) {
#pragma unroll
    for (int reg = 0; reg < 4; ++reg) {
      const int n = row0 + wr + i * 16 + q4 * 4 + reg;
      if (n >= N) continue;
      const long long nrow = (long long)n * M;
#pragma unroll
      for (int j = 0; j < 4; ++j) {
        const int m = col0 + wc + j * 16 + r16;
        float v = acc[i][j][reg];
        if (MODE == 0) {
          if (m < 1024) outU[(long long)n * 1024 + m] = f2bf(v + bias[m]);
          else outU2[(long long)n * 1024 + m - 1024] = f2bf(v + bias2[m - 1024]);
        } else if (MODE == 1) {
          const int p = n - batch * rpb;
          v += ep[(long long)p * 1024 + m];
          if (p == m) v = -1e9f;
          outF[nrow + m] = v;
        } else if (MODE == 2) {
          outU[nrow + m] = f2bf(v + bias[bias_off + m]);
        } else if (MODE == 3) {
          outU[nrow + m] = f2bf(gelu_f(v + bias[bias_off + m]));
        } else {
          if (bias) v += bias[bias_off + m];
          v += ep[nrow + m];
          outF[nrow + m] = v;
        }
      }
    }
  }
}

// ---- top-32: one wave per row, values in registers, shuffle argmax ----
__global__ __launch_bounds__(256) void topk_kernel(const float* __restrict__ scores,
                                                   int* __restrict__ routes,
                                                   float* __restrict__ logw) {
  const int row = blockIdx.x * 4 + (threadIdx.x >> 6);
  const int lane = threadIdx.x & 63;
  const float* sr = scores + (long long)row * P_;
  float v[16];
#pragma unroll
  for (int j = 0; j < 16; ++j) v[j] = sr[j * 64 + lane];
  float selv = 0.f;
  int seli = 0;
  for (int t = 0; t < K_; ++t) {
    float bv = v[0];
    int bj = 0;
#pragma unroll
    for (int j = 1; j < 16; ++j)
      if (v[j] > bv) { bv = v[j]; bj = j; }
    int bi = bj * 64 + lane;
#pragma unroll
    for (int off = 1; off < 64; off <<= 1) {
      float ov = __shfl_xor(bv, off);
      int oi = __shfl_xor(bi, off);
      if (ov > bv || (ov == bv && oi < bi)) { bv = ov; bi = oi; }
    }
    if (lane == t) { selv = bv; seli = bi; }
    if ((bi & 63) == lane) v[bi >> 6] = -3.0e38f;
  }
  const float sc = selv * (1.0f / TEMP_);
  const float mt = __shfl(sc, 0);  // first pick is the max
  float e = (lane < K_) ? expf(sc - mt) : 0.f;
  float sum = e;
#pragma unroll
  for (int off = 1; off < 64; off <<= 1) sum += __shfl_xor(sum, off);
  if (lane < K_) {
    const float lw = sc - mt - logf(sum);
    logw[(long long)row * K_ + lane] = fmaxf(lw, -10.0f);
    routes[(long long)row * K_ + lane] = seli;
  }
}

// ---- cls-token attention: one block (256 thr) per (b,h), bf16 qkv ----
__global__ __launch_bounds__(256) void attn_cls_kernel(const u16* __restrict__ qkv,
                                                       u16* __restrict__ out) {
  __shared__ float qs[HD_];
  __shared__ float lg[S_];
  __shared__ float red4[4];
  __shared__ float sacc[4][HD_];
  const int b = blockIdx.x >> 4;
  const int h = blockIdx.x & 15;
  const int tid = threadIdx.x;
  const int lane = tid & 63;
  const int wv = tid >> 6;
  const long long base = (long long)b * S_ * 3072;
  if (tid < HD_) qs[tid] = bf2f(qkv[base + h * HD_ + tid]);
  __syncthreads();
  float lmax = -3.0e38f;
  for (int s = tid; s < S_; s += 256) {
    const u16* kp = qkv + base + (long long)s * 3072 + 1024 + h * HD_;
    float d = 0.f;
#pragma unroll
    for (int c = 0; c < 8; ++c) {
      short8 kv = *reinterpret_cast<const short8*>(kp + c * 8);
#pragma unroll
      for (int e = 0; e < 8; ++e) d += qs[c * 8 + e] * bf2f((u16)kv[e]);
    }
    d *= SCALE_;
    lg[s] = d;
    lmax = fmaxf(lmax, d);
  }
  const float m = block_max256(lmax, red4);
  float sum = 0.f;
  for (int s = tid; s < S_; s += 256) {
    float e = expf(lg[s] - m);
    lg[s] = e;
    sum += e;
  }
  const float tot = block_sum256(sum, red4);
  __syncthreads();
  float acc = 0.f;
  for (int s = wv; s < S_; s += 4)
    acc += lg[s] * bf2f(qkv[base + (long long)s * 3072 + 2048 + h * HD_ + lane]);
  sacc[wv][lane] = acc;
  __syncthreads();
  if (tid < HD_) {
    float a = sacc[0][tid] + sacc[1][tid] + sacc[2][tid] + sacc[3][tid];
    out[(long long)b * S_ * D_ + h * HD_ + tid] = f2bf(a / tot);
  }
}

// ---- routed patch attention: one block (64 thr = 1 wave) per (b,p,h) ----
__global__ __launch_bounds__(64) void attn_patch_kernel(const u16* __restrict__ qkv,
                                                        const int* __restrict__ routes,
                                                        const float* __restrict__ logw,
                                                        u16* __restrict__ out) {
  __shared__ float qs[HD_];
  __shared__ float wk[K_];
  __shared__ int sidx[K_];
  const int bid = blockIdx.x;
  const int h = bid & 15;
  const int p = (bid >> 4) & (P_ - 1);
  const int b = bid >> 14;
  const int tid = threadIdx.x;
  const long long base = (long long)b * S_ * 3072;
  qs[tid] = bf2f(qkv[base + (long long)(1 + p) * 3072 + h * HD_ + tid]);
  __syncthreads();
  float lg = -3.0e38f;
  if (tid < K_) {
    const long long ro = ((long long)(b * P_ + p)) * K_ + tid;
    const int r = routes[ro];
    sidx[tid] = r;
    const u16* kp = qkv + base + (long long)(1 + r) * 3072 + 1024 + h * HD_;
    float d = 0.f;
#pragma unroll
    for (int c = 0; c < 8; ++c) {
      short8 kv = *reinterpret_cast<const short8*>(kp + c * 8);
#pragma unroll
      for (int e = 0; e < 8; ++e) d += qs[c * 8 + e] * bf2f((u16)kv[e]);
    }
    lg = d * SCALE_ + logw[ro];
  }
  // softmax over lanes 0..31 (xor<=16 stays within the 32-group)
  float m = lg;
#pragma unroll
  for (int off = 1; off < 32; off <<= 1) m = fmaxf(m, __shfl_xor(m, off));
  float e = (tid < K_) ? expf(lg - m) : 0.f;
  float sum = e;
#pragma unroll
  for (int off = 1; off < 32; off <<= 1) sum += __shfl_xor(sum, off);
  if (tid < K_) wk[tid] = e / sum;
  __syncthreads();
  float acc = 0.f;
#pragma unroll 4
  for (int k = 0; k < K_; ++k)
    acc += wk[k] * bf2f(qkv[base + (long long)(1 + sidx[k]) * 3072 + 2048 + h * HD_ + tid]);
  out[((long long)b * S_ + 1 + p) * D_ + h * HD_ + tid] = f2bf(acc);
}

extern "C" void kernel_launch(void* const* d_in, const int* in_sizes, int n_in,
                              void* d_out, int out_size, void* d_ws, size_t ws_size,
                              hipStream_t stream) {
  const float* x      = (const float*)d_in[0];
  const float* n1w    = (const float*)d_in[1];
  const float* n1b    = (const float*)d_in[2];
  const float* rq_w   = (const float*)d_in[3];
  const float* rq_b   = (const float*)d_in[4];
  const float* rk_w   = (const float*)d_in[5];
  const float* rk_b   = (const float*)d_in[6];
  const float* pos    = (const float*)d_in[7];
  const float* qkv_w  = (const float*)d_in[8];
  const float* qkv_b  = (const float*)d_in[9];
  const float* proj_w = (const float*)d_in[10];
  const float* proj_b = (const float*)d_in[11];
  const float* n2w    = (const float*)d_in[12];
  const float* n2b    = (const float*)d_in[13];
  const float* fc1_w  = (const float*)d_in[14];
  const float* fc1_b  = (const float*)d_in[15];
  const float* fc2_w  = (const float*)d_in[16];
  const float* fc2_b  = (const float*)d_in[17];

  // ---- workspace layout (bytes, all 16B aligned; total ~40.4 MB) ----
  char* mem = (char*)d_ws;
  int*   routes = (int*)mem;                        //   262,144
  float* logw   = (float*)(mem + 262144);           //   262,144
  u16*   wslot  = (u16*)(mem + 524288);             // 6,291,456 (JIT-converted weights)
  u16*   xnorm  = (u16*)(mem + 6815744);            // 4,198,400 (2050x1024 bf16)
  u16*   qr     = (u16*)(mem + 11014144);           // 4,198,400 (qr, later attn)
  u16*   attn   = qr;
  u16*   kr     = (u16*)(mem + 15212544);           // 4,194,304
  char*  big    = mem + 19406848;                   // 12,595,200 (scores|qkvb|hbuf)
  float* scores = (float*)big;
  u16*   qkvb   = (u16*)big;
  u16*   hbuf   = (u16*)big;
  float* x1     = (float*)(mem + 32002048);         // 8,396,800 (2050x1024 f32)

  // 1. LN1: x -> xnorm (bf16)
  ln_kernel<<<B_ * S_, 256, 0, stream>>>(x, n1w, n1b, xnorm);

  // 2. fused rq|rk GEMM (weights cat into wslot), then l2norm
  conv_kernel<<<1024, 256, 0, stream>>>(rq_w, 0, 1024, wslot, 1 << 20, 10);
  conv_kernel<<<1024, 256, 0, stream>>>(rk_w, 0, 1024, wslot + (1 << 20), 1 << 20, 10);
  mfma_gemm<0><<<dim3(16, 16), 256, 0, stream>>>(xnorm, 1024LL, wslot,
      2048, 2048, 1024, 1024, (long long)S_ * D_, 0LL,
      rq_b, rk_b, 0, nullptr, qr, kr, nullptr);
  l2norm_kernel<<<2048, 256, 0, stream>>>(qr);
  l2norm_kernel<<<2048, 256, 0, stream>>>(kr);

  // 3. scores = qr . kr^T + pos, diag=-1e9 (batched)
  mfma_gemm<1><<<dim3(8, 16), 256, 0, stream>>>(qr, 0LL, kr,
      2048, 1024, 1024, 1024, 1LL << 20, 1LL << 20,
      nullptr, nullptr, 0, pos, nullptr, nullptr, scores);

  // 4. top-32 routing
  topk_kernel<<<512, 256, 0, stream>>>(scores, routes, logw);

  // 5. qkv GEMM (scores dead -> big slot reused)
  conv_kernel<<<3072, 256, 0, stream>>>(qkv_w, 0, 1024, wslot, 3 << 20, 10);
  mfma_gemm<2><<<dim3(24, 17), 256, 0, stream>>>(xnorm, 0LL, wslot,
      2050, 3072, 1024, 2050, 0LL, 0LL,
      qkv_b, nullptr, 0, nullptr, qkvb, nullptr, nullptr);

  // 6. attention -> attn (bf16)
  attn_cls_kernel<<<B_ * H_, 256, 0, stream>>>(qkvb, attn);
  attn_patch_kernel<<<B_ * P_ * H_, 64, 0, stream>>>(qkvb, routes, logw, attn);

  // 7. proj + residual(x) -> x1 (f32)
  conv_kernel<<<1024, 256, 0, stream>>>(proj_w, 0, 1024, wslot, 1 << 20, 10);
  mfma_gemm<4><<<dim3(8, 17), 256, 0, stream>>>(attn, 0LL, wslot,
      2050, 1024, 1024, 2050, 0LL, 0LL,
      proj_b, nullptr, 0, x, nullptr, nullptr, x1);

  // 8. LN2: x1 -> xnorm (bf16)
  ln_kernel<<<B_ * S_, 256, 0, stream>>>(x1, n2w, n2b, xnorm);

  // 9. MLP in two K-halves (hbuf = 2050x2048 bf16 in big slot)
  conv_kernel<<<2048, 256, 0, stream>>>(fc1_w, 0, 1024, wslot, 1 << 21, 10);
  mfma_gemm<3><<<dim3(16, 17), 256, 0, stream>>>(xnorm, 0LL, wslot,
      2050, 2048, 1024, 2050, 0LL, 0LL,
      fc1_b, nullptr, 0, nullptr, hbuf, nullptr, nullptr);
  conv_kernel<<<2048, 256, 0, stream>>>(fc2_w, 0, 4096, wslot, 1 << 21, 11);
  mfma_gemm<4><<<dim3(8, 17), 256, 0, stream>>>(hbuf, 0LL, wslot,
      2050, 1024, 2048, 2050, 0LL, 0LL,
      fc2_b, nullptr, 0, x1, nullptr, nullptr, x1);
  conv_kernel<<<2048, 256, 0, stream>>>(fc1_w, (long long)2048 * 1024, 1024, wslot, 1 << 21, 10);
  mfma_gemm<3><<<dim3(16, 17), 256, 0, stream>>>(xnorm, 0LL, wslot,
      2050, 2048, 1024, 2050, 0LL, 0LL,
      fc1_b, nullptr, 2048, nullptr, hbuf, nullptr, nullptr);
  conv_kernel<<<2048, 256, 0, stream>>>(fc2_w, 2048, 4096, wslot, 1 << 21, 11);
  mfma_gemm<4><<<dim3(8, 17), 256, 0, stream>>>(hbuf, 0LL, wslot,
      2050, 1024, 2048, 2050, 0LL, 0LL,
      nullptr, nullptr, 0, x1, nullptr, nullptr, (float*)d_out);
}

// Round 6
// 524.395 us; speedup vs baseline: 5.5736x; 1.1949x over previous
//
#include <hip/hip_runtime.h>
#include <hip/hip_bf16.h>
#include <math.h>

typedef unsigned short u16;
typedef __attribute__((ext_vector_type(8))) short short8;
typedef __attribute__((ext_vector_type(4))) float f32x4;

#define B_ 2
#define S_ 1025
#define D_ 1024
#define H_ 16
#define HD_ 64
#define P_ 1024
#define K_ 32
#define NS_ 16   // attn_cls S-splits

static constexpr float TEMP_ = 0.1f;
static constexpr float SCALE_ = 0.125f;
static constexpr float EPS_LN_ = 1e-5f;

__device__ __forceinline__ float bf2f(u16 u) {
  unsigned int t = ((unsigned int)u) << 16;
  float f;
  __builtin_memcpy(&f, &t, 4);
  return f;
}
__device__ __forceinline__ u16 f2bf(float f) {
  __hip_bfloat16 h = __float2bfloat16(f);
  u16 u;
  __builtin_memcpy(&u, &h, 2);
  return u;
}
__device__ __forceinline__ float gelu_f(float x) {
  return 0.5f * x * (1.0f + erff(x * 0.70710678118654752f));
}

typedef __attribute__((address_space(1))) const unsigned int gas_u32;
typedef __attribute__((address_space(3))) unsigned int las_u32;
__device__ __forceinline__ void g2l16(const void* g, void* l) {
  __builtin_amdgcn_global_load_lds((gas_u32*)g, (las_u32*)l, 16, 0, 0);
}

// ---- weight convert f32 -> bf16, [M,Kd] row-major dst ----
__global__ __launch_bounds__(256) void conv_kernel(const float* __restrict__ src,
                                                   long long soff, int sstr,
                                                   u16* __restrict__ dst,
                                                   int total, int kshift) {
  int e = (blockIdx.x * 256 + threadIdx.x) * 4;
  if (e >= total) return;
  int m = e >> kshift;
  int k = e - (m << kshift);
  float4 t = *reinterpret_cast<const float4*>(src + soff + (long long)m * sstr + k);
  ushort4 o;
  o.x = f2bf(t.x); o.y = f2bf(t.y); o.z = f2bf(t.z); o.w = f2bf(t.w);
  *reinterpret_cast<ushort4*>(dst + e) = o;
}

// ---- block reductions (256 threads) ----
__device__ __forceinline__ float block_sum256(float v, float* red4) {
  for (int off = 32; off > 0; off >>= 1) v += __shfl_down(v, off);
  if ((threadIdx.x & 63) == 0) red4[threadIdx.x >> 6] = v;
  __syncthreads();
  float r = red4[0] + red4[1] + red4[2] + red4[3];
  __syncthreads();
  return r;
}
__device__ __forceinline__ float block_max256(float v, float* red4) {
  for (int off = 32; off > 0; off >>= 1) v = fmaxf(v, __shfl_down(v, off));
  if ((threadIdx.x & 63) == 0) red4[threadIdx.x >> 6] = v;
  __syncthreads();
  float r = fmaxf(fmaxf(red4[0], red4[1]), fmaxf(red4[2], red4[3]));
  __syncthreads();
  return r;
}

// ---- LayerNorm f32 in -> bf16 out ----
__global__ __launch_bounds__(256) void ln_kernel(const float* __restrict__ x,
                                                 const float* __restrict__ w,
                                                 const float* __restrict__ b,
                                                 u16* __restrict__ out) {
  __shared__ float red4[4];
  const long long base = (long long)blockIdx.x * D_;
  float v[4];
  float s = 0.f, ss = 0.f;
#pragma unroll
  for (int u = 0; u < 4; ++u) {
    int d = threadIdx.x + u * 256;
    float f = x[base + d];
    v[u] = f; s += f; ss += f * f;
  }
  float tot = block_sum256(s, red4);
  float tot2 = block_sum256(ss, red4);
  float mean = tot * (1.0f / D_);
  float var = tot2 * (1.0f / D_) - mean * mean;
  float rstd = rsqrtf(var + EPS_LN_);
#pragma unroll
  for (int u = 0; u < 4; ++u) {
    int d = threadIdx.x + u * 256;
    out[base + d] = f2bf((v[u] - mean) * rstd * w[d] + b[d]);
  }
}

// ---- L2 normalize rows in-place (bf16) ----
__global__ __launch_bounds__(256) void l2norm_kernel(u16* __restrict__ x) {
  __shared__ float red4[4];
  const long long base = (long long)blockIdx.x * D_;
  float v[4];
  float ss = 0.f;
#pragma unroll
  for (int u = 0; u < 4; ++u) {
    int d = threadIdx.x + u * 256;
    v[u] = bf2f(x[base + d]);
    ss += v[u] * v[u];
  }
  float tot = block_sum256(ss, red4);
  float inv = 1.0f / fmaxf(sqrtf(tot), 1e-12f);
#pragma unroll
  for (int u = 0; u < 4; ++u) {
    int d = threadIdx.x + u * 256;
    x[base + d] = f2bf(v[u] * inv);
  }
}

// ---- MFMA GEMM (see r5 notes): out[n,m] = sum_k A[n,k]*W[m,k] ----
template <int MODE>
__global__ __launch_bounds__(256, 2) void mfma_gemm(
    const u16* __restrict__ A, long long a_off, const u16* __restrict__ W,
    int N, int M, int Kd, int rpb, long long a_bs, long long w_bs,
    const float* __restrict__ bias, const float* __restrict__ bias2, int bias_off,
    const float* __restrict__ ep,
    u16* __restrict__ outU, u16* __restrict__ outU2, float* __restrict__ outF) {
  __shared__ u16 sA[128 * 32];
  __shared__ u16 sW[128 * 32];
  const int tid = threadIdx.x;
  const int lane = tid & 63;
  const int q4 = lane >> 4;
  const int r16 = lane & 15;
  const int wave = tid >> 6;
  const int wr = (wave >> 1) * 64;
  const int wc = (wave & 1) * 64;
  const int row0 = blockIdx.y * 128;
  const int col0 = blockIdx.x * 128;
  const int batch = row0 / rpb;
  const u16* Ab = A + a_off + (long long)batch * a_bs +
                  (long long)(row0 - batch * rpb) * Kd;
  const u16* Wb = W + (long long)batch * w_bs + (long long)col0 * Kd;
  const int srow = tid >> 2;
  const int sko = (tid & 3) * 8;
  const int rmax = N - 1 - row0;
  const long long aoff0 = (long long)min(srow, rmax) * Kd + sko;
  const long long aoff1 = (long long)min(srow + 64, rmax) * Kd + sko;
  const long long woff0 = (long long)srow * Kd + sko;
  const long long woff1 = (long long)(srow + 64) * Kd + sko;
  f32x4 acc[4][4] = {};
  for (int k0 = 0; k0 < Kd; k0 += 32) {
    g2l16(Ab + aoff0 + k0, &sA[tid * 8]);
    g2l16(Ab + aoff1 + k0, &sA[2048 + tid * 8]);
    g2l16(Wb + woff0 + k0, &sW[tid * 8]);
    g2l16(Wb + woff1 + k0, &sW[2048 + tid * 8]);
    __builtin_amdgcn_s_waitcnt(0);
    __syncthreads();
    short8 a[4], b[4];
#pragma unroll
    for (int i = 0; i < 4; ++i)
      a[i] = *reinterpret_cast<const short8*>(&sA[(wr + i * 16 + r16) * 32 + q4 * 8]);
#pragma unroll
    for (int j = 0; j < 4; ++j)
      b[j] = *reinterpret_cast<const short8*>(&sW[(wc + j * 16 + r16) * 32 + q4 * 8]);
#pragma unroll
    for (int i = 0; i < 4; ++i)
#pragma unroll
      for (int j = 0; j < 4; ++j)
        acc[i][j] = __builtin_amdgcn_mfma_f32_16x16x32_bf16(a[i], b[j], acc[i][j], 0, 0, 0);
    __syncthreads();
  }
#pragma unroll
  for (int i = 0; i < 4; ++i) {
#pragma unroll
    for (int reg = 0; reg < 4; ++reg) {
      const int n = row0 + wr + i * 16 + q4 * 4 + reg;
      if (n >= N) continue;
      const long long nrow = (long long)n * M;
#pragma unroll
      for (int j = 0; j < 4; ++j) {
        const int m = col0 + wc + j * 16 + r16;
        float v = acc[i][j][reg];
        if (MODE == 0) {
          if (m < 1024) outU[(long long)n * 1024 + m] = f2bf(v + bias[m]);
          else outU2[(long long)n * 1024 + m - 1024] = f2bf(v + bias2[m - 1024]);
        } else if (MODE == 1) {
          const int p = n - batch * rpb;
          v += ep[(long long)p * 1024 + m];
          if (p == m) v = -1e9f;
          outF[nrow + m] = v;
        } else if (MODE == 2) {
          outU[nrow + m] = f2bf(v + bias[bias_off + m]);
        } else if (MODE == 3) {
          outU[nrow + m] = f2bf(gelu_f(v + bias[bias_off + m]));
        } else {
          if (bias) v += bias[bias_off + m];
          v += ep[nrow + m];
          outF[nrow + m] = v;
        }
      }
    }
  }
}

// ---- top-32: one wave per row ----
__global__ __launch_bounds__(256) void topk_kernel(const float* __restrict__ scores,
                                                   int* __restrict__ routes,
                                                   float* __restrict__ logw) {
  const int row = blockIdx.x * 4 + (threadIdx.x >> 6);
  const int lane = threadIdx.x & 63;
  const float* sr = scores + (long long)row * P_;
  float v[16];
#pragma unroll
  for (int j = 0; j < 16; ++j) v[j] = sr[j * 64 + lane];
  float selv = 0.f;
  int seli = 0;
  for (int t = 0; t < K_; ++t) {
    float bv = v[0];
    int bj = 0;
#pragma unroll
    for (int j = 1; j < 16; ++j)
      if (v[j] > bv) { bv = v[j]; bj = j; }
    int bi = bj * 64 + lane;
#pragma unroll
    for (int off = 1; off < 64; off <<= 1) {
      float ov = __shfl_xor(bv, off);
      int oi = __shfl_xor(bi, off);
      if (ov > bv || (ov == bv && oi < bi)) { bv = ov; bi = oi; }
    }
    if (lane == t) { selv = bv; seli = bi; }
    if ((bi & 63) == lane) v[bi >> 6] = -3.0e38f;
  }
  const float sc = selv * (1.0f / TEMP_);
  const float mt = __shfl(sc, 0);
  float e = (lane < K_) ? expf(sc - mt) : 0.f;
  float sum = e;
#pragma unroll
  for (int off = 1; off < 64; off <<= 1) sum += __shfl_xor(sum, off);
  if (lane < K_) {
    const float lw = sc - mt - logf(sum);
    logw[(long long)row * K_ + lane] = fmaxf(lw, -10.0f);
    routes[(long long)row * K_ + lane] = seli;
  }
}

// ---- cls attention phase 1: grid (NS_, B*H); chunked online stats ----
// part[bh][ck]: [0..63]=partial weighted V, [64]=m_c, [65]=l_c
__global__ __launch_bounds__(256) void attn_cls_p1(const u16* __restrict__ qkv,
                                                   float* __restrict__ part) {
  __shared__ float qs[HD_];
  __shared__ float lg[65];
  __shared__ float red4[4];
  __shared__ float sacc[4][HD_];
  const int ck = blockIdx.x;
  const int bh = blockIdx.y;
  const int b = bh >> 4, h = bh & 15;
  const int tid = threadIdx.x;
  const int lane = tid & 63;
  const int wv = tid >> 6;
  const int s0 = ck * 65;
  const int rows = min(65, S_ - s0);
  const long long base = (long long)b * S_ * 3072;
  if (tid < HD_) qs[tid] = bf2f(qkv[base + h * HD_ + tid]);
  __syncthreads();
  float lmax = -3.0e38f;
  if (tid < rows) {
    const u16* kp = qkv + base + (long long)(s0 + tid) * 3072 + 1024 + h * HD_;
    float d = 0.f;
#pragma unroll
    for (int c = 0; c < 8; ++c) {
      short8 kv = *reinterpret_cast<const short8*>(kp + c * 8);
#pragma unroll
      for (int e = 0; e < 8; ++e) d += qs[c * 8 + e] * bf2f((u16)kv[e]);
    }
    d *= SCALE_;
    lg[tid] = d;
    lmax = d;
  }
  const float m = block_max256(lmax, red4);
  float e = 0.f;
  if (tid < rows) {
    e = expf(lg[tid] - m);
    lg[tid] = e;
  }
  const float l = block_sum256(e, red4);
  __syncthreads();
  float acc = 0.f;
  for (int r = wv; r < rows; r += 4)
    acc += lg[r] * bf2f(qkv[base + (long long)(s0 + r) * 3072 + 2048 + h * HD_ + lane]);
  sacc[wv][lane] = acc;
  __syncthreads();
  float* pc = part + ((long long)bh * NS_ + ck) * 66;
  if (tid < HD_)
    pc[tid] = sacc[0][tid] + sacc[1][tid] + sacc[2][tid] + sacc[3][tid];
  if (tid == 64) pc[64] = m;
  if (tid == 65) pc[65] = l;
}

// ---- cls attention phase 2: combine chunks; one block (64 thr) per (b,h) ----
__global__ __launch_bounds__(64) void attn_cls_p2(const float* __restrict__ part,
                                                  u16* __restrict__ out) {
  const int bh = blockIdx.x;
  const int b = bh >> 4, h = bh & 15;
  const int tid = threadIdx.x;
  const float* pb = part + (long long)bh * NS_ * 66;
  float M = -3.0e38f;
#pragma unroll
  for (int c = 0; c < NS_; ++c) M = fmaxf(M, pb[c * 66 + 64]);
  float L = 0.f, a = 0.f;
#pragma unroll
  for (int c = 0; c < NS_; ++c) {
    const float w = expf(pb[c * 66 + 64] - M);
    L += pb[c * 66 + 65] * w;
    a += pb[c * 66 + tid] * w;
  }
  out[(long long)b * S_ * D_ + h * HD_ + tid] = f2bf(a / L);
}

// ---- routed patch attention: one wave per (b,p,h) ----
__global__ __launch_bounds__(64) void attn_patch_kernel(const u16* __restrict__ qkv,
                                                        const int* __restrict__ routes,
                                                        const float* __restrict__ logw,
                                                        u16* __restrict__ out) {
  __shared__ float qs[HD_];
  __shared__ float wk[K_];
  __shared__ int sidx[K_];
  const int bid = blockIdx.x;
  const int h = bid & 15;
  const int p = (bid >> 4) & (P_ - 1);
  const int b = bid >> 14;
  const int tid = threadIdx.x;
  const long long base = (long long)b * S_ * 3072;
  qs[tid] = bf2f(qkv[base + (long long)(1 + p) * 3072 + h * HD_ + tid]);
  __syncthreads();
  float lg = -3.0e38f;
  if (tid < K_) {
    const long long ro = ((long long)(b * P_ + p)) * K_ + tid;
    const int r = routes[ro];
    sidx[tid] = r;
    const u16* kp = qkv + base + (long long)(1 + r) * 3072 + 1024 + h * HD_;
    float d = 0.f;
#pragma unroll
    for (int c = 0; c < 8; ++c) {
      short8 kv = *reinterpret_cast<const short8*>(kp + c * 8);
#pragma unroll
      for (int e = 0; e < 8; ++e) d += qs[c * 8 + e] * bf2f((u16)kv[e]);
    }
    lg = d * SCALE_ + logw[ro];
  }
  float m = lg;
#pragma unroll
  for (int off = 1; off < 32; off <<= 1) m = fmaxf(m, __shfl_xor(m, off));
  float e = (tid < K_) ? expf(lg - m) : 0.f;
  float sum = e;
#pragma unroll
  for (int off = 1; off < 32; off <<= 1) sum += __shfl_xor(sum, off);
  if (tid < K_) wk[tid] = e / sum;
  __syncthreads();
  float acc = 0.f;
#pragma unroll 4
  for (int k = 0; k < K_; ++k)
    acc += wk[k] * bf2f(qkv[base + (long long)(1 + sidx[k]) * 3072 + 2048 + h * HD_ + tid]);
  out[((long long)b * S_ + 1 + p) * D_ + h * HD_ + tid] = f2bf(acc);
}

extern "C" void kernel_launch(void* const* d_in, const int* in_sizes, int n_in,
                              void* d_out, int out_size, void* d_ws, size_t ws_size,
                              hipStream_t stream) {
  const float* x      = (const float*)d_in[0];
  const float* n1w    = (const float*)d_in[1];
  const float* n1b    = (const float*)d_in[2];
  const float* rq_w   = (const float*)d_in[3];
  const float* rq_b   = (const float*)d_in[4];
  const float* rk_w   = (const float*)d_in[5];
  const float* rk_b   = (const float*)d_in[6];
  const float* pos    = (const float*)d_in[7];
  const float* qkv_w  = (const float*)d_in[8];
  const float* qkv_b  = (const float*)d_in[9];
  const float* proj_w = (const float*)d_in[10];
  const float* proj_b = (const float*)d_in[11];
  const float* n2w    = (const float*)d_in[12];
  const float* n2b    = (const float*)d_in[13];
  const float* fc1_w  = (const float*)d_in[14];
  const float* fc1_b  = (const float*)d_in[15];
  const float* fc2_w  = (const float*)d_in[16];
  const float* fc2_b  = (const float*)d_in[17];

  // ---- workspace layout (bytes; total ~44.8 MB; evidence: ws >= 59.3 MB) ----
  char* mem = (char*)d_ws;
  int*   routes = (int*)mem;                        //   262,144
  float* logw   = (float*)(mem + 262144);           //   262,144
  float* part   = (float*)(mem + 524288);           //   262,144 (cls partials: 32*16*66 f32)
  u16*   wslot  = (u16*)(mem + 786432);             // 8,388,608 (JIT bf16 weights)
  u16*   xnorm  = (u16*)(mem + 9175040);            // 4,198,400
  u16*   qr     = (u16*)(mem + 13373440);           // 4,198,400 (qr, later attn)
  u16*   attn   = qr;
  u16*   kr     = (u16*)(mem + 17571840);           // 4,194,304
  char*  big    = mem + 21766144;                   // 16,793,600 (scores|qkvb|hbuf)
  float* scores = (float*)big;
  u16*   qkvb   = (u16*)big;
  u16*   hbuf   = (u16*)big;
  float* x1     = (float*)(mem + 38559744);         // 8,396,800

  // 1. LN1: x -> xnorm (bf16)
  ln_kernel<<<B_ * S_, 256, 0, stream>>>(x, n1w, n1b, xnorm);

  // 2. fused rq|rk GEMM, then l2norm
  conv_kernel<<<1024, 256, 0, stream>>>(rq_w, 0, 1024, wslot, 1 << 20, 10);
  conv_kernel<<<1024, 256, 0, stream>>>(rk_w, 0, 1024, wslot + (1 << 20), 1 << 20, 10);
  mfma_gemm<0><<<dim3(16, 16), 256, 0, stream>>>(xnorm, 1024LL, wslot,
      2048, 2048, 1024, 1024, (long long)S_ * D_, 0LL,
      rq_b, rk_b, 0, nullptr, qr, kr, nullptr);
  l2norm_kernel<<<2048, 256, 0, stream>>>(qr);
  l2norm_kernel<<<2048, 256, 0, stream>>>(kr);

  // 3. scores = qr . kr^T + pos, diag=-1e9 (batched)
  mfma_gemm<1><<<dim3(8, 16), 256, 0, stream>>>(qr, 0LL, kr,
      2048, 1024, 1024, 1024, 1LL << 20, 1LL << 20,
      nullptr, nullptr, 0, pos, nullptr, nullptr, scores);

  // 4. top-32 routing
  topk_kernel<<<512, 256, 0, stream>>>(scores, routes, logw);

  // 5. qkv GEMM (big slot reused)
  conv_kernel<<<3072, 256, 0, stream>>>(qkv_w, 0, 1024, wslot, 3 << 20, 10);
  mfma_gemm<2><<<dim3(24, 17), 256, 0, stream>>>(xnorm, 0LL, wslot,
      2050, 3072, 1024, 2050, 0LL, 0LL,
      qkv_b, nullptr, 0, nullptr, qkvb, nullptr, nullptr);

  // 6. attention -> attn (bf16): split-S cls + routed patch
  attn_cls_p1<<<dim3(NS_, B_ * H_), 256, 0, stream>>>(qkvb, part);
  attn_cls_p2<<<B_ * H_, 64, 0, stream>>>(part, attn);
  attn_patch_kernel<<<B_ * P_ * H_, 64, 0, stream>>>(qkvb, routes, logw, attn);

  // 7. proj + residual(x) -> x1 (f32)
  conv_kernel<<<1024, 256, 0, stream>>>(proj_w, 0, 1024, wslot, 1 << 20, 10);
  mfma_gemm<4><<<dim3(8, 17), 256, 0, stream>>>(attn, 0LL, wslot,
      2050, 1024, 1024, 2050, 0LL, 0LL,
      proj_b, nullptr, 0, x, nullptr, nullptr, x1);

  // 8. LN2: x1 -> xnorm (bf16)
  ln_kernel<<<B_ * S_, 256, 0, stream>>>(x1, n2w, n2b, xnorm);

  // 9. MLP, unsplit: fc1 (2050x4096x1024) -> hbuf; fc2 (2050x1024x4096) -> d_out
  conv_kernel<<<4096, 256, 0, stream>>>(fc1_w, 0, 1024, wslot, 1 << 22, 10);
  mfma_gemm<3><<<dim3(32, 17), 256, 0, stream>>>(xnorm, 0LL, wslot,
      2050, 4096, 1024, 2050, 0LL, 0LL,
      fc1_b, nullptr, 0, nullptr, hbuf, nullptr, nullptr);
  conv_kernel<<<4096, 256, 0, stream>>>(fc2_w, 0, 4096, wslot, 1 << 22, 12);
  mfma_gemm<4><<<dim3(8, 17), 256, 0, stream>>>(hbuf, 0LL, wslot,
      2050, 1024, 4096, 2050, 0LL, 0LL,
      fc2_b, nullptr, 0, x1, nullptr, nullptr, (float*)d_out);
}

// Round 7
// 452.948 us; speedup vs baseline: 6.4528x; 1.1577x over previous
//
#include <hip/hip_runtime.h>
#include <hip/hip_bf16.h>
#include <math.h>

typedef unsigned short u16;
typedef __attribute__((ext_vector_type(8))) short short8;
typedef __attribute__((ext_vector_type(4))) float f32x4;

#define B_ 2
#define S_ 1025
#define D_ 1024
#define H_ 16
#define HD_ 64
#define P_ 1024
#define K_ 32
#define NS_ 16   // attn_cls S-splits

static constexpr float TEMP_ = 0.1f;
static constexpr float SCALE_ = 0.125f;
static constexpr float EPS_LN_ = 1e-5f;

__device__ __forceinline__ float bf2f(u16 u) {
  unsigned int t = ((unsigned int)u) << 16;
  float f;
  __builtin_memcpy(&f, &t, 4);
  return f;
}
__device__ __forceinline__ u16 f2bf(float f) {
  __hip_bfloat16 h = __float2bfloat16(f);
  u16 u;
  __builtin_memcpy(&u, &h, 2);
  return u;
}
__device__ __forceinline__ float gelu_f(float x) {
  return 0.5f * x * (1.0f + erff(x * 0.70710678118654752f));
}

typedef __attribute__((address_space(1))) const unsigned int gas_u32;
typedef __attribute__((address_space(3))) unsigned int las_u32;
__device__ __forceinline__ void g2l16(const void* g, void* l) {
  __builtin_amdgcn_global_load_lds((gas_u32*)g, (las_u32*)l, 16, 0, 0);
}

// ---- weight convert f32 -> bf16, [M,Kd] row-major dst ----
__global__ __launch_bounds__(256) void conv_kernel(const float* __restrict__ src,
                                                   long long soff, int sstr,
                                                   u16* __restrict__ dst,
                                                   int total, int kshift) {
  int e = (blockIdx.x * 256 + threadIdx.x) * 4;
  if (e >= total) return;
  int m = e >> kshift;
  int k = e - (m << kshift);
  float4 t = *reinterpret_cast<const float4*>(src + soff + (long long)m * sstr + k);
  ushort4 o;
  o.x = f2bf(t.x); o.y = f2bf(t.y); o.z = f2bf(t.z); o.w = f2bf(t.w);
  *reinterpret_cast<ushort4*>(dst + e) = o;
}

// ---- out[n,m] = a[n,m] + bias[m], f32, one block per row (D=1024) ----
__global__ __launch_bounds__(256) void init_addb(const float* __restrict__ a,
                                                 const float* __restrict__ bias,
                                                 float* __restrict__ out) {
  const long long base = (long long)blockIdx.x * D_;
#pragma unroll
  for (int u = 0; u < 4; ++u) {
    int d = threadIdx.x + u * 256;
    out[base + d] = a[base + d] + bias[d];
  }
}

// ---- scores init: scores[b,p,q] = pos[p,q], diag -1e9; block per (b,p) ----
__global__ __launch_bounds__(256) void init_scores(const float* __restrict__ pos,
                                                   float* __restrict__ scores) {
  const int bp = blockIdx.x;
  const int p = bp & (P_ - 1);
  const long long base = (long long)bp * P_;
#pragma unroll
  for (int u = 0; u < 4; ++u) {
    int q = threadIdx.x + u * 256;
    float v = pos[(long long)p * P_ + q];
    if (p == q) v = -1e9f;
    scores[base + q] = v;
  }
}

// ---- block reductions (256 threads) ----
__device__ __forceinline__ float block_sum256(float v, float* red4) {
  for (int off = 32; off > 0; off >>= 1) v += __shfl_down(v, off);
  if ((threadIdx.x & 63) == 0) red4[threadIdx.x >> 6] = v;
  __syncthreads();
  float r = red4[0] + red4[1] + red4[2] + red4[3];
  __syncthreads();
  return r;
}
__device__ __forceinline__ float block_max256(float v, float* red4) {
  for (int off = 32; off > 0; off >>= 1) v = fmaxf(v, __shfl_down(v, off));
  if ((threadIdx.x & 63) == 0) red4[threadIdx.x >> 6] = v;
  __syncthreads();
  float r = fmaxf(fmaxf(red4[0], red4[1]), fmaxf(red4[2], red4[3]));
  __syncthreads();
  return r;
}

// ---- LayerNorm f32 in -> bf16 out ----
__global__ __launch_bounds__(256) void ln_kernel(const float* __restrict__ x,
                                                 const float* __restrict__ w,
                                                 const float* __restrict__ b,
                                                 u16* __restrict__ out) {
  __shared__ float red4[4];
  const long long base = (long long)blockIdx.x * D_;
  float v[4];
  float s = 0.f, ss = 0.f;
#pragma unroll
  for (int u = 0; u < 4; ++u) {
    int d = threadIdx.x + u * 256;
    float f = x[base + d];
    v[u] = f; s += f; ss += f * f;
  }
  float tot = block_sum256(s, red4);
  float tot2 = block_sum256(ss, red4);
  float mean = tot * (1.0f / D_);
  float var = tot2 * (1.0f / D_) - mean * mean;
  float rstd = rsqrtf(var + EPS_LN_);
#pragma unroll
  for (int u = 0; u < 4; ++u) {
    int d = threadIdx.x + u * 256;
    out[base + d] = f2bf((v[u] - mean) * rstd * w[d] + b[d]);
  }
}

// ---- L2 normalize rows in-place (bf16) ----
__global__ __launch_bounds__(256) void l2norm_kernel(u16* __restrict__ x) {
  __shared__ float red4[4];
  const long long base = (long long)blockIdx.x * D_;
  float v[4];
  float ss = 0.f;
#pragma unroll
  for (int u = 0; u < 4; ++u) {
    int d = threadIdx.x + u * 256;
    v[u] = bf2f(x[base + d]);
    ss += v[u] * v[u];
  }
  float tot = block_sum256(ss, red4);
  float inv = 1.0f / fmaxf(sqrtf(tot), 1e-12f);
#pragma unroll
  for (int u = 0; u < 4; ++u) {
    int d = threadIdx.x + u * 256;
    x[base + d] = f2bf(v[u] * inv);
  }
}

// ---- MFMA GEMM: out[n,m] = sum_k A[n,k]*W[m,k], 128x128 tile ----
// MODE 0: RQK   : m<1024 -> outU=bf16(v+bias[m]); else outU2=bf16(v+bias2[m-1024])
// MODE 2: BIAS  : outU = bf16(v + bias[bias_off+m])
// MODE 3: GELU  : outU = bf16(gelu(v + bias[bias_off+m]))
// MODE 5: ACC   : unsafeAtomicAdd(outF[n*M+m], v)   (split-K; blockIdx.z = k-slice)
template <int MODE>
__global__ __launch_bounds__(256, 3) void mfma_gemm(
    const u16* __restrict__ A, long long a_off, const u16* __restrict__ W,
    int N, int M, int Kd, int klen, int rpb, long long a_bs, long long w_bs,
    const float* __restrict__ bias, const float* __restrict__ bias2, int bias_off,
    u16* __restrict__ outU, u16* __restrict__ outU2, float* __restrict__ outF) {
  __shared__ u16 sA[128 * 32];
  __shared__ u16 sW[128 * 32];
  const int tid = threadIdx.x;
  const int lane = tid & 63;
  const int q4 = lane >> 4;
  const int r16 = lane & 15;
  const int wave = tid >> 6;
  const int wr = (wave >> 1) * 64;
  const int wc = (wave & 1) * 64;
  const int row0 = blockIdx.y * 128;
  const int col0 = blockIdx.x * 128;
  const int batch = row0 / rpb;
  const u16* Ab = A + a_off + (long long)batch * a_bs +
                  (long long)(row0 - batch * rpb) * Kd;
  const u16* Wb = W + (long long)batch * w_bs + (long long)col0 * Kd;
  const int srow = tid >> 2;
  const int sko = (tid & 3) * 8;
  const int rmax = N - 1 - row0;
  const long long aoff0 = (long long)min(srow, rmax) * Kd + sko;
  const long long aoff1 = (long long)min(srow + 64, rmax) * Kd + sko;
  const long long woff0 = (long long)srow * Kd + sko;
  const long long woff1 = (long long)(srow + 64) * Kd + sko;
  const int kbeg = blockIdx.z * klen;
  f32x4 acc[4][4] = {};
  for (int k0 = kbeg; k0 < kbeg + klen; k0 += 32) {
    g2l16(Ab + aoff0 + k0, &sA[tid * 8]);
    g2l16(Ab + aoff1 + k0, &sA[2048 + tid * 8]);
    g2l16(Wb + woff0 + k0, &sW[tid * 8]);
    g2l16(Wb + woff1 + k0, &sW[2048 + tid * 8]);
    __builtin_amdgcn_s_waitcnt(0);
    __syncthreads();
    short8 a[4], b[4];
#pragma unroll
    for (int i = 0; i < 4; ++i)
      a[i] = *reinterpret_cast<const short8*>(&sA[(wr + i * 16 + r16) * 32 + q4 * 8]);
#pragma unroll
    for (int j = 0; j < 4; ++j)
      b[j] = *reinterpret_cast<const short8*>(&sW[(wc + j * 16 + r16) * 32 + q4 * 8]);
#pragma unroll
    for (int i = 0; i < 4; ++i)
#pragma unroll
      for (int j = 0; j < 4; ++j)
        acc[i][j] = __builtin_amdgcn_mfma_f32_16x16x32_bf16(a[i], b[j], acc[i][j], 0, 0, 0);
    __syncthreads();
  }
#pragma unroll
  for (int i = 0; i < 4; ++i) {
#pragma unroll
    for (int reg = 0; reg < 4; ++reg) {
      const int n = row0 + wr + i * 16 + q4 * 4 + reg;
      if (n >= N) continue;
      const long long nrow = (long long)n * M;
#pragma unroll
      for (int j = 0; j < 4; ++j) {
        const int m = col0 + wc + j * 16 + r16;
        float v = acc[i][j][reg];
        if (MODE == 0) {
          if (m < 1024) outU[(long long)n * 1024 + m] = f2bf(v + bias[m]);
          else outU2[(long long)n * 1024 + m - 1024] = f2bf(v + bias2[m - 1024]);
        } else if (MODE == 2) {
          outU[nrow + m] = f2bf(v + bias[bias_off + m]);
        } else if (MODE == 3) {
          outU[nrow + m] = f2bf(gelu_f(v + bias[bias_off + m]));
        } else {
          unsafeAtomicAdd(&outF[nrow + m], v);
        }
      }
    }
  }
}

// ---- top-32: one wave per row ----
__global__ __launch_bounds__(256) void topk_kernel(const float* __restrict__ scores,
                                                   int* __restrict__ routes,
                                                   float* __restrict__ logw) {
  const int row = blockIdx.x * 4 + (threadIdx.x >> 6);
  const int lane = threadIdx.x & 63;
  const float* sr = scores + (long long)row * P_;
  float v[16];
#pragma unroll
  for (int j = 0; j < 16; ++j) v[j] = sr[j * 64 + lane];
  float selv = 0.f;
  int seli = 0;
  for (int t = 0; t < K_; ++t) {
    float bv = v[0];
    int bj = 0;
#pragma unroll
    for (int j = 1; j < 16; ++j)
      if (v[j] > bv) { bv = v[j]; bj = j; }
    int bi = bj * 64 + lane;
#pragma unroll
    for (int off = 1; off < 64; off <<= 1) {
      float ov = __shfl_xor(bv, off);
      int oi = __shfl_xor(bi, off);
      if (ov > bv || (ov == bv && oi < bi)) { bv = ov; bi = oi; }
    }
    if (lane == t) { selv = bv; seli = bi; }
    if ((bi & 63) == lane) v[bi >> 6] = -3.0e38f;
  }
  const float sc = selv * (1.0f / TEMP_);
  const float mt = __shfl(sc, 0);
  float e = (lane < K_) ? expf(sc - mt) : 0.f;
  float sum = e;
#pragma unroll
  for (int off = 1; off < 64; off <<= 1) sum += __shfl_xor(sum, off);
  if (lane < K_) {
    const float lw = sc - mt - logf(sum);
    logw[(long long)row * K_ + lane] = fmaxf(lw, -10.0f);
    routes[(long long)row * K_ + lane] = seli;
  }
}

// ---- cls attention phase 1: grid (NS_, B*H); chunked online stats ----
__global__ __launch_bounds__(256) void attn_cls_p1(const u16* __restrict__ qkv,
                                                   float* __restrict__ part) {
  __shared__ float qs[HD_];
  __shared__ float lg[65];
  __shared__ float red4[4];
  __shared__ float sacc[4][HD_];
  const int ck = blockIdx.x;
  const int bh = blockIdx.y;
  const int b = bh >> 4, h = bh & 15;
  const int tid = threadIdx.x;
  const int lane = tid & 63;
  const int wv = tid >> 6;
  const int s0 = ck * 65;
  const int rows = min(65, S_ - s0);
  const long long base = (long long)b * S_ * 3072;
  if (tid < HD_) qs[tid] = bf2f(qkv[base + h * HD_ + tid]);
  __syncthreads();
  float lmax = -3.0e38f;
  if (tid < rows) {
    const u16* kp = qkv + base + (long long)(s0 + tid) * 3072 + 1024 + h * HD_;
    float d = 0.f;
#pragma unroll
    for (int c = 0; c < 8; ++c) {
      short8 kv = *reinterpret_cast<const short8*>(kp + c * 8);
#pragma unroll
      for (int e = 0; e < 8; ++e) d += qs[c * 8 + e] * bf2f((u16)kv[e]);
    }
    d *= SCALE_;
    lg[tid] = d;
    lmax = d;
  }
  const float m = block_max256(lmax, red4);
  float e = 0.f;
  if (tid < rows) {
    e = expf(lg[tid] - m);
    lg[tid] = e;
  }
  const float l = block_sum256(e, red4);
  __syncthreads();
  float acc = 0.f;
  for (int r = wv; r < rows; r += 4)
    acc += lg[r] * bf2f(qkv[base + (long long)(s0 + r) * 3072 + 2048 + h * HD_ + lane]);
  sacc[wv][lane] = acc;
  __syncthreads();
  float* pc = part + ((long long)bh * NS_ + ck) * 66;
  if (tid < HD_)
    pc[tid] = sacc[0][tid] + sacc[1][tid] + sacc[2][tid] + sacc[3][tid];
  if (tid == 64) pc[64] = m;
  if (tid == 65) pc[65] = l;
}

// ---- cls attention phase 2: combine; one block (64 thr) per (b,h) ----
__global__ __launch_bounds__(64) void attn_cls_p2(const float* __restrict__ part,
                                                  u16* __restrict__ out) {
  const int bh = blockIdx.x;
  const int b = bh >> 4, h = bh & 15;
  const int tid = threadIdx.x;
  const float* pb = part + (long long)bh * NS_ * 66;
  float M = -3.0e38f;
#pragma unroll
  for (int c = 0; c < NS_; ++c) M = fmaxf(M, pb[c * 66 + 64]);
  float L = 0.f, a = 0.f;
#pragma unroll
  for (int c = 0; c < NS_; ++c) {
    const float w = expf(pb[c * 66 + 64] - M);
    L += pb[c * 66 + 65] * w;
    a += pb[c * 66 + tid] * w;
  }
  out[(long long)b * S_ * D_ + h * HD_ + tid] = f2bf(a / L);
}

// ---- routed patch attention: one wave per (b,p,h) ----
__global__ __launch_bounds__(64) void attn_patch_kernel(const u16* __restrict__ qkv,
                                                        const int* __restrict__ routes,
                                                        const float* __restrict__ logw,
                                                        u16* __restrict__ out) {
  __shared__ float qs[HD_];
  __shared__ float wk[K_];
  __shared__ int sidx[K_];
  const int bid = blockIdx.x;
  const int h = bid & 15;
  const int p = (bid >> 4) & (P_ - 1);
  const int b = bid >> 14;
  const int tid = threadIdx.x;
  const long long base = (long long)b * S_ * 3072;
  qs[tid] = bf2f(qkv[base + (long long)(1 + p) * 3072 + h * HD_ + tid]);
  __syncthreads();
  float lg = -3.0e38f;
  if (tid < K_) {
    const long long ro = ((long long)(b * P_ + p)) * K_ + tid;
    const int r = routes[ro];
    sidx[tid] = r;
    const u16* kp = qkv + base + (long long)(1 + r) * 3072 + 1024 + h * HD_;
    float d = 0.f;
#pragma unroll
    for (int c = 0; c < 8; ++c) {
      short8 kv = *reinterpret_cast<const short8*>(kp + c * 8);
#pragma unroll
      for (int e = 0; e < 8; ++e) d += qs[c * 8 + e] * bf2f((u16)kv[e]);
    }
    lg = d * SCALE_ + logw[ro];
  }
  float m = lg;
#pragma unroll
  for (int off = 1; off < 32; off <<= 1) m = fmaxf(m, __shfl_xor(m, off));
  float e = (tid < K_) ? expf(lg - m) : 0.f;
  float sum = e;
#pragma unroll
  for (int off = 1; off < 32; off <<= 1) sum += __shfl_xor(sum, off);
  if (tid < K_) wk[tid] = e / sum;
  __syncthreads();
  float acc = 0.f;
#pragma unroll 4
  for (int k = 0; k < K_; ++k)
    acc += wk[k] * bf2f(qkv[base + (long long)(1 + sidx[k]) * 3072 + 2048 + h * HD_ + tid]);
  out[((long long)b * S_ + 1 + p) * D_ + h * HD_ + tid] = f2bf(acc);
}

extern "C" void kernel_launch(void* const* d_in, const int* in_sizes, int n_in,
                              void* d_out, int out_size, void* d_ws, size_t ws_size,
                              hipStream_t stream) {
  const float* x      = (const float*)d_in[0];
  const float* n1w    = (const float*)d_in[1];
  const float* n1b    = (const float*)d_in[2];
  const float* rq_w   = (const float*)d_in[3];
  const float* rq_b   = (const float*)d_in[4];
  const float* rk_w   = (const float*)d_in[5];
  const float* rk_b   = (const float*)d_in[6];
  const float* pos    = (const float*)d_in[7];
  const float* qkv_w  = (const float*)d_in[8];
  const float* qkv_b  = (const float*)d_in[9];
  const float* proj_w = (const float*)d_in[10];
  const float* proj_b = (const float*)d_in[11];
  const float* n2w    = (const float*)d_in[12];
  const float* n2b    = (const float*)d_in[13];
  const float* fc1_w  = (const float*)d_in[14];
  const float* fc1_b  = (const float*)d_in[15];
  const float* fc2_w  = (const float*)d_in[16];
  const float* fc2_b  = (const float*)d_in[17];
  float* out = (float*)d_out;

  // ---- workspace layout (bytes; total ~44.8 MB; evidence: ws >= 59.3 MB) ----
  char* mem = (char*)d_ws;
  int*   routes = (int*)mem;                        //   262,144
  float* logw   = (float*)(mem + 262144);           //   262,144
  float* part   = (float*)(mem + 524288);           //   262,144
  u16*   wslot  = (u16*)(mem + 786432);             // 8,388,608 (JIT bf16 weights)
  u16*   xnorm  = (u16*)(mem + 9175040);            // 4,198,400
  u16*   qr     = (u16*)(mem + 13373440);           // 4,198,400 (qr, later attn)
  u16*   attn   = qr;
  u16*   kr     = (u16*)(mem + 17571840);           // 4,194,304
  char*  big    = mem + 21766144;                   // 16,793,600 (scores|qkvb|hbuf)
  float* scores = (float*)big;
  u16*   qkvb   = (u16*)big;
  u16*   hbuf   = (u16*)big;
  float* x1     = (float*)(mem + 38559744);         // 8,396,800

  // 1. LN1: x -> xnorm (bf16)
  ln_kernel<<<B_ * S_, 256, 0, stream>>>(x, n1w, n1b, xnorm);

  // 2. fused rq|rk GEMM, then l2norm
  conv_kernel<<<1024, 256, 0, stream>>>(rq_w, 0, 1024, wslot, 1 << 20, 10);
  conv_kernel<<<1024, 256, 0, stream>>>(rk_w, 0, 1024, wslot + (1 << 20), 1 << 20, 10);
  mfma_gemm<0><<<dim3(16, 16), 256, 0, stream>>>(xnorm, 1024LL, wslot,
      2048, 2048, 1024, 1024, 1024, (long long)S_ * D_, 0LL,
      rq_b, rk_b, 0, qr, kr, nullptr);
  l2norm_kernel<<<2048, 256, 0, stream>>>(qr);
  l2norm_kernel<<<2048, 256, 0, stream>>>(kr);

  // 3. scores = pos (+diag) then split-K x2 atomic accumulate of qr.kr^T
  init_scores<<<B_ * P_, 256, 0, stream>>>(pos, scores);
  mfma_gemm<5><<<dim3(8, 16, 2), 256, 0, stream>>>(qr, 0LL, kr,
      2048, 1024, 1024, 512, 1024, 1LL << 20, 1LL << 20,
      nullptr, nullptr, 0, nullptr, nullptr, scores);

  // 4. top-32 routing
  topk_kernel<<<512, 256, 0, stream>>>(scores, routes, logw);

  // 5. qkv GEMM (big slot reused)
  conv_kernel<<<3072, 256, 0, stream>>>(qkv_w, 0, 1024, wslot, 3 << 20, 10);
  mfma_gemm<2><<<dim3(24, 17), 256, 0, stream>>>(xnorm, 0LL, wslot,
      2050, 3072, 1024, 1024, 2050, 0LL, 0LL,
      qkv_b, nullptr, 0, qkvb, nullptr, nullptr);

  // 6. attention -> attn (bf16)
  attn_cls_p1<<<dim3(NS_, B_ * H_), 256, 0, stream>>>(qkvb, part);
  attn_cls_p2<<<B_ * H_, 64, 0, stream>>>(part, attn);
  attn_patch_kernel<<<B_ * P_ * H_, 64, 0, stream>>>(qkvb, routes, logw, attn);

  // 7. proj: x1 = x + proj_b, then split-K x2 atomic accumulate
  conv_kernel<<<1024, 256, 0, stream>>>(proj_w, 0, 1024, wslot, 1 << 20, 10);
  init_addb<<<B_ * S_, 256, 0, stream>>>(x, proj_b, x1);
  mfma_gemm<5><<<dim3(8, 17, 2), 256, 0, stream>>>(attn, 0LL, wslot,
      2050, 1024, 1024, 512, 2050, 0LL, 0LL,
      nullptr, nullptr, 0, nullptr, nullptr, x1);

  // 8. LN2: x1 -> xnorm (bf16)
  ln_kernel<<<B_ * S_, 256, 0, stream>>>(x1, n2w, n2b, xnorm);

  // 9. MLP: fc1 -> hbuf (bf16); fc2 split-K x4 atomic into d_out = x1 + fc2_b
  conv_kernel<<<4096, 256, 0, stream>>>(fc1_w, 0, 1024, wslot, 1 << 22, 10);
  mfma_gemm<3><<<dim3(32, 17), 256, 0, stream>>>(xnorm, 0LL, wslot,
      2050, 4096, 1024, 1024, 2050, 0LL, 0LL,
      fc1_b, nullptr, 0, hbuf, nullptr, nullptr);
  conv_kernel<<<4096, 256, 0, stream>>>(fc2_w, 0, 4096, wslot, 1 << 22, 12);
  init_addb<<<B_ * S_, 256, 0, stream>>>(x1, fc2_b, out);
  mfma_gemm<5><<<dim3(8, 17, 4), 256, 0, stream>>>(hbuf, 0LL, wslot,
      2050, 1024, 4096, 1024, 2050, 0LL, 0LL,
      nullptr, nullptr, 0, nullptr, nullptr, out);
}

// Round 8
// 435.603 us; speedup vs baseline: 6.7098x; 1.0398x over previous
//
#include <hip/hip_runtime.h>
#include <hip/hip_bf16.h>
#include <math.h>

typedef unsigned short u16;
typedef __attribute__((ext_vector_type(8))) short short8;
typedef __attribute__((ext_vector_type(4))) float f32x4;

#define B_ 2
#define S_ 1025
#define D_ 1024
#define H_ 16
#define HD_ 64
#define P_ 1024
#define K_ 32
#define NS_ 16   // attn_cls S-splits

static constexpr float TEMP_ = 0.1f;
static constexpr float SCALE_ = 0.125f;
static constexpr float EPS_LN_ = 1e-5f;

__device__ __forceinline__ float bf2f(u16 u) {
  unsigned int t = ((unsigned int)u) << 16;
  float f;
  __builtin_memcpy(&f, &t, 4);
  return f;
}
__device__ __forceinline__ u16 f2bf(float f) {
  __hip_bfloat16 h = __float2bfloat16(f);
  u16 u;
  __builtin_memcpy(&u, &h, 2);
  return u;
}
__device__ __forceinline__ float gelu_f(float x) {
  return 0.5f * x * (1.0f + erff(x * 0.70710678118654752f));
}

typedef __attribute__((address_space(1))) const unsigned int gas_u32;
typedef __attribute__((address_space(3))) unsigned int las_u32;
__device__ __forceinline__ void g2l16(const void* g, void* l) {
  __builtin_amdgcn_global_load_lds((gas_u32*)g, (las_u32*)l, 16, 0, 0);
}

// ---- weight convert f32 -> bf16, [M,Kd] row-major dst ----
__global__ __launch_bounds__(256) void conv_kernel(const float* __restrict__ src,
                                                   long long soff, int sstr,
                                                   u16* __restrict__ dst,
                                                   int total, int kshift) {
  int e = (blockIdx.x * 256 + threadIdx.x) * 4;
  if (e >= total) return;
  int m = e >> kshift;
  int k = e - (m << kshift);
  float4 t = *reinterpret_cast<const float4*>(src + soff + (long long)m * sstr + k);
  ushort4 o;
  o.x = f2bf(t.x); o.y = f2bf(t.y); o.z = f2bf(t.z); o.w = f2bf(t.w);
  *reinterpret_cast<ushort4*>(dst + e) = o;
}

// ---- out[n,m] = a[n,m] + bias[m], f32, one block per row (D=1024) ----
__global__ __launch_bounds__(256) void init_addb(const float* __restrict__ a,
                                                 const float* __restrict__ bias,
                                                 float* __restrict__ out) {
  const long long base = (long long)blockIdx.x * D_;
#pragma unroll
  for (int u = 0; u < 4; ++u) {
    int d = threadIdx.x + u * 256;
    out[base + d] = a[base + d] + bias[d];
  }
}

// ---- scores init: scores[b,p,q] = pos[p,q], diag -1e9; block per (b,p) ----
__global__ __launch_bounds__(256) void init_scores(const float* __restrict__ pos,
                                                   float* __restrict__ scores) {
  const int bp = blockIdx.x;
  const int p = bp & (P_ - 1);
  const long long base = (long long)bp * P_;
#pragma unroll
  for (int u = 0; u < 4; ++u) {
    int q = threadIdx.x + u * 256;
    float v = pos[(long long)p * P_ + q];
    if (p == q) v = -1e9f;
    scores[base + q] = v;
  }
}

// ---- block reductions (256 threads) ----
__device__ __forceinline__ float block_sum256(float v, float* red4) {
  for (int off = 32; off > 0; off >>= 1) v += __shfl_down(v, off);
  if ((threadIdx.x & 63) == 0) red4[threadIdx.x >> 6] = v;
  __syncthreads();
  float r = red4[0] + red4[1] + red4[2] + red4[3];
  __syncthreads();
  return r;
}
__device__ __forceinline__ float block_max256(float v, float* red4) {
  for (int off = 32; off > 0; off >>= 1) v = fmaxf(v, __shfl_down(v, off));
  if ((threadIdx.x & 63) == 0) red4[threadIdx.x >> 6] = v;
  __syncthreads();
  float r = fmaxf(fmaxf(red4[0], red4[1]), fmaxf(red4[2], red4[3]));
  __syncthreads();
  return r;
}

// ---- LayerNorm f32 in -> bf16 out ----
__global__ __launch_bounds__(256) void ln_kernel(const float* __restrict__ x,
                                                 const float* __restrict__ w,
                                                 const float* __restrict__ b,
                                                 u16* __restrict__ out) {
  __shared__ float red4[4];
  const long long base = (long long)blockIdx.x * D_;
  float v[4];
  float s = 0.f, ss = 0.f;
#pragma unroll
  for (int u = 0; u < 4; ++u) {
    int d = threadIdx.x + u * 256;
    float f = x[base + d];
    v[u] = f; s += f; ss += f * f;
  }
  float tot = block_sum256(s, red4);
  float tot2 = block_sum256(ss, red4);
  float mean = tot * (1.0f / D_);
  float var = tot2 * (1.0f / D_) - mean * mean;
  float rstd = rsqrtf(var + EPS_LN_);
#pragma unroll
  for (int u = 0; u < 4; ++u) {
    int d = threadIdx.x + u * 256;
    out[base + d] = f2bf((v[u] - mean) * rstd * w[d] + b[d]);
  }
}

// ---- L2 normalize rows in-place (bf16) ----
__global__ __launch_bounds__(256) void l2norm_kernel(u16* __restrict__ x) {
  __shared__ float red4[4];
  const long long base = (long long)blockIdx.x * D_;
  float v[4];
  float ss = 0.f;
#pragma unroll
  for (int u = 0; u < 4; ++u) {
    int d = threadIdx.x + u * 256;
    v[u] = bf2f(x[base + d]);
    ss += v[u] * v[u];
  }
  float tot = block_sum256(ss, red4);
  float inv = 1.0f / fmaxf(sqrtf(tot), 1e-12f);
#pragma unroll
  for (int u = 0; u < 4; ++u) {
    int d = threadIdx.x + u * 256;
    x[base + d] = f2bf(v[u] * inv);
  }
}

// ---- MFMA GEMM: out[n,m] = sum_k A[n,k]*W[m,k], 128x128 tile, BK=64 ----
// LDS layout: [row][k 0..63] u16, k granules (16B) XOR-swizzled by (row&7) so
// fragment ds_read_b128 lands 2-way on banks (global_load_lds forbids padding;
// the swizzle is applied on the GLOBAL source address, LDS dest stays linear).
// MODE 0: RQK   : m<1024 -> outU=bf16(v+bias[m]); else outU2=bf16(v+bias2[m-1024])
// MODE 2: BIAS  : outU = bf16(v + bias[bias_off+m])
// MODE 3: GELU  : outU = bf16(gelu(v + bias[bias_off+m]))
// MODE 5: ACC   : unsafeAtomicAdd(outF[n*M+m], v)   (split-K; blockIdx.z = k-slice)
template <int MODE>
__global__ __launch_bounds__(256, 2) void mfma_gemm(
    const u16* __restrict__ A, long long a_off, const u16* __restrict__ W,
    int N, int M, int Kd, int klen, int rpb, long long a_bs, long long w_bs,
    const float* __restrict__ bias, const float* __restrict__ bias2, int bias_off,
    u16* __restrict__ outU, u16* __restrict__ outU2, float* __restrict__ outF) {
  __shared__ u16 sA[128 * 64];
  __shared__ u16 sW[128 * 64];
  const int tid = threadIdx.x;
  const int lane = tid & 63;
  const int q4 = lane >> 4;
  const int r16 = lane & 15;
  const int wave = tid >> 6;
  const int wr = (wave >> 1) * 64;
  const int wc = (wave & 1) * 64;
  const int row0 = blockIdx.y * 128;
  const int col0 = blockIdx.x * 128;
  const int batch = row0 / rpb;
  const u16* Ab = A + a_off + (long long)batch * a_bs +
                  (long long)(row0 - batch * rpb) * Kd;
  const u16* Wb = W + (long long)batch * w_bs + (long long)col0 * Kd;
  const int rmax = N - 1 - row0;
  // staging: 4 chunks of (32 rows x 64 k); lds dest = c*2048 + tid*8 (u16)
  const int srow = tid >> 3;                     // row within chunk (0..31)
  const int kx = ((tid & 7) ^ (srow & 7)) * 8;   // swizzled global k-offset
  long long aoffs[4], woffs[4];
#pragma unroll
  for (int c = 0; c < 4; ++c) {
    const int rg = c * 32 + srow;
    aoffs[c] = (long long)min(rg, rmax) * Kd + kx;
    woffs[c] = (long long)rg * Kd + kx;
  }
  const int kbeg = blockIdx.z * klen;
  f32x4 acc[4][4] = {};
  for (int k0 = kbeg; k0 < kbeg + klen; k0 += 64) {
#pragma unroll
    for (int c = 0; c < 4; ++c) {
      g2l16(Ab + aoffs[c] + k0, &sA[c * 2048 + tid * 8]);
      g2l16(Wb + woffs[c] + k0, &sW[c * 2048 + tid * 8]);
    }
    __builtin_amdgcn_s_waitcnt(0);
    __syncthreads();
    short8 a[2][4], b[2][4];
#pragma unroll
    for (int s = 0; s < 2; ++s) {
      const int ks = ((s * 4 + q4) ^ (r16 & 7)) * 8;
#pragma unroll
      for (int i = 0; i < 4; ++i) {
        a[s][i] = *reinterpret_cast<const short8*>(&sA[(wr + i * 16 + r16) * 64 + ks]);
        b[s][i] = *reinterpret_cast<const short8*>(&sW[(wc + i * 16 + r16) * 64 + ks]);
      }
    }
#pragma unroll
    for (int s = 0; s < 2; ++s)
#pragma unroll
      for (int i = 0; i < 4; ++i)
#pragma unroll
        for (int j = 0; j < 4; ++j)
          acc[i][j] = __builtin_amdgcn_mfma_f32_16x16x32_bf16(a[s][i], b[s][j],
                                                              acc[i][j], 0, 0, 0);
    __syncthreads();
  }
#pragma unroll
  for (int i = 0; i < 4; ++i) {
#pragma unroll
    for (int reg = 0; reg < 4; ++reg) {
      const int n = row0 + wr + i * 16 + q4 * 4 + reg;
      if (n >= N) continue;
      const long long nrow = (long long)n * M;
#pragma unroll
      for (int j = 0; j < 4; ++j) {
        const int m = col0 + wc + j * 16 + r16;
        float v = acc[i][j][reg];
        if (MODE == 0) {
          if (m < 1024) outU[(long long)n * 1024 + m] = f2bf(v + bias[m]);
          else outU2[(long long)n * 1024 + m - 1024] = f2bf(v + bias2[m - 1024]);
        } else if (MODE == 2) {
          outU[nrow + m] = f2bf(v + bias[bias_off + m]);
        } else if (MODE == 3) {
          outU[nrow + m] = f2bf(gelu_f(v + bias[bias_off + m]));
        } else {
          unsafeAtomicAdd(&outF[nrow + m], v);
        }
      }
    }
  }
}

// ---- top-32: one wave per row ----
__global__ __launch_bounds__(256) void topk_kernel(const float* __restrict__ scores,
                                                   int* __restrict__ routes,
                                                   float* __restrict__ logw) {
  const int row = blockIdx.x * 4 + (threadIdx.x >> 6);
  const int lane = threadIdx.x & 63;
  const float* sr = scores + (long long)row * P_;
  float v[16];
#pragma unroll
  for (int j = 0; j < 16; ++j) v[j] = sr[j * 64 + lane];
  float selv = 0.f;
  int seli = 0;
  for (int t = 0; t < K_; ++t) {
    float bv = v[0];
    int bj = 0;
#pragma unroll
    for (int j = 1; j < 16; ++j)
      if (v[j] > bv) { bv = v[j]; bj = j; }
    int bi = bj * 64 + lane;
#pragma unroll
    for (int off = 1; off < 64; off <<= 1) {
      float ov = __shfl_xor(bv, off);
      int oi = __shfl_xor(bi, off);
      if (ov > bv || (ov == bv && oi < bi)) { bv = ov; bi = oi; }
    }
    if (lane == t) { selv = bv; seli = bi; }
    if ((bi & 63) == lane) v[bi >> 6] = -3.0e38f;
  }
  const float sc = selv * (1.0f / TEMP_);
  const float mt = __shfl(sc, 0);
  float e = (lane < K_) ? expf(sc - mt) : 0.f;
  float sum = e;
#pragma unroll
  for (int off = 1; off < 64; off <<= 1) sum += __shfl_xor(sum, off);
  if (lane < K_) {
    const float lw = sc - mt - logf(sum);
    logw[(long long)row * K_ + lane] = fmaxf(lw, -10.0f);
    routes[(long long)row * K_ + lane] = seli;
  }
}

// ---- cls attention phase 1: grid (NS_, B*H); chunked online stats ----
__global__ __launch_bounds__(256) void attn_cls_p1(const u16* __restrict__ qkv,
                                                   float* __restrict__ part) {
  __shared__ float qs[HD_];
  __shared__ float lg[65];
  __shared__ float red4[4];
  __shared__ float sacc[4][HD_];
  const int ck = blockIdx.x;
  const int bh = blockIdx.y;
  const int b = bh >> 4, h = bh & 15;
  const int tid = threadIdx.x;
  const int lane = tid & 63;
  const int wv = tid >> 6;
  const int s0 = ck * 65;
  const int rows = min(65, S_ - s0);
  const long long base = (long long)b * S_ * 3072;
  if (tid < HD_) qs[tid] = bf2f(qkv[base + h * HD_ + tid]);
  __syncthreads();
  float lmax = -3.0e38f;
  if (tid < rows) {
    const u16* kp = qkv + base + (long long)(s0 + tid) * 3072 + 1024 + h * HD_;
    float d = 0.f;
#pragma unroll
    for (int c = 0; c < 8; ++c) {
      short8 kv = *reinterpret_cast<const short8*>(kp + c * 8);
#pragma unroll
      for (int e = 0; e < 8; ++e) d += qs[c * 8 + e] * bf2f((u16)kv[e]);
    }
    d *= SCALE_;
    lg[tid] = d;
    lmax = d;
  }
  const float m = block_max256(lmax, red4);
  float e = 0.f;
  if (tid < rows) {
    e = expf(lg[tid] - m);
    lg[tid] = e;
  }
  const float l = block_sum256(e, red4);
  __syncthreads();
  float acc = 0.f;
  for (int r = wv; r < rows; r += 4)
    acc += lg[r] * bf2f(qkv[base + (long long)(s0 + r) * 3072 + 2048 + h * HD_ + lane]);
  sacc[wv][lane] = acc;
  __syncthreads();
  float* pc = part + ((long long)bh * NS_ + ck) * 66;
  if (tid < HD_)
    pc[tid] = sacc[0][tid] + sacc[1][tid] + sacc[2][tid] + sacc[3][tid];
  if (tid == 64) pc[64] = m;
  if (tid == 65) pc[65] = l;
}

// ---- cls attention phase 2: combine; one block (64 thr) per (b,h) ----
__global__ __launch_bounds__(64) void attn_cls_p2(const float* __restrict__ part,
                                                  u16* __restrict__ out) {
  const int bh = blockIdx.x;
  const int b = bh >> 4, h = bh & 15;
  const int tid = threadIdx.x;
  const float* pb = part + (long long)bh * NS_ * 66;
  float M = -3.0e38f;
#pragma unroll
  for (int c = 0; c < NS_; ++c) M = fmaxf(M, pb[c * 66 + 64]);
  float L = 0.f, a = 0.f;
#pragma unroll
  for (int c = 0; c < NS_; ++c) {
    const float w = expf(pb[c * 66 + 64] - M);
    L += pb[c * 66 + 65] * w;
    a += pb[c * 66 + tid] * w;
  }
  out[(long long)b * S_ * D_ + h * HD_ + tid] = f2bf(a / L);
}

// ---- routed patch attention: one wave per (b,p,h) ----
__global__ __launch_bounds__(64) void attn_patch_kernel(const u16* __restrict__ qkv,
                                                        const int* __restrict__ routes,
                                                        const float* __restrict__ logw,
                                                        u16* __restrict__ out) {
  __shared__ float qs[HD_];
  __shared__ float wk[K_];
  __shared__ int sidx[K_];
  const int bid = blockIdx.x;
  const int h = bid & 15;
  const int p = (bid >> 4) & (P_ - 1);
  const int b = bid >> 14;
  const int tid = threadIdx.x;
  const long long base = (long long)b * S_ * 3072;
  qs[tid] = bf2f(qkv[base + (long long)(1 + p) * 3072 + h * HD_ + tid]);
  __syncthreads();
  float lg = -3.0e38f;
  if (tid < K_) {
    const long long ro = ((long long)(b * P_ + p)) * K_ + tid;
    const int r = routes[ro];
    sidx[tid] = r;
    const u16* kp = qkv + base + (long long)(1 + r) * 3072 + 1024 + h * HD_;
    float d = 0.f;
#pragma unroll
    for (int c = 0; c < 8; ++c) {
      short8 kv = *reinterpret_cast<const short8*>(kp + c * 8);
#pragma unroll
      for (int e = 0; e < 8; ++e) d += qs[c * 8 + e] * bf2f((u16)kv[e]);
    }
    lg = d * SCALE_ + logw[ro];
  }
  float m = lg;
#pragma unroll
  for (int off = 1; off < 32; off <<= 1) m = fmaxf(m, __shfl_xor(m, off));
  float e = (tid < K_) ? expf(lg - m) : 0.f;
  float sum = e;
#pragma unroll
  for (int off = 1; off < 32; off <<= 1) sum += __shfl_xor(sum, off);
  if (tid < K_) wk[tid] = e / sum;
  __syncthreads();
  float acc = 0.f;
#pragma unroll 4
  for (int k = 0; k < K_; ++k)
    acc += wk[k] * bf2f(qkv[base + (long long)(1 + sidx[k]) * 3072 + 2048 + h * HD_ + tid]);
  out[((long long)b * S_ + 1 + p) * D_ + h * HD_ + tid] = f2bf(acc);
}

extern "C" void kernel_launch(void* const* d_in, const int* in_sizes, int n_in,
                              void* d_out, int out_size, void* d_ws, size_t ws_size,
                              hipStream_t stream) {
  const float* x      = (const float*)d_in[0];
  const float* n1w    = (const float*)d_in[1];
  const float* n1b    = (const float*)d_in[2];
  const float* rq_w   = (const float*)d_in[3];
  const float* rq_b   = (const float*)d_in[4];
  const float* rk_w   = (const float*)d_in[5];
  const float* rk_b   = (const float*)d_in[6];
  const float* pos    = (const float*)d_in[7];
  const float* qkv_w  = (const float*)d_in[8];
  const float* qkv_b  = (const float*)d_in[9];
  const float* proj_w = (const float*)d_in[10];
  const float* proj_b = (const float*)d_in[11];
  const float* n2w    = (const float*)d_in[12];
  const float* n2b    = (const float*)d_in[13];
  const float* fc1_w  = (const float*)d_in[14];
  const float* fc1_b  = (const float*)d_in[15];
  const float* fc2_w  = (const float*)d_in[16];
  const float* fc2_b  = (const float*)d_in[17];
  float* out = (float*)d_out;

  // ---- workspace layout (bytes; total ~44.8 MB; evidence: ws >= 59.3 MB) ----
  char* mem = (char*)d_ws;
  int*   routes = (int*)mem;                        //   262,144
  float* logw   = (float*)(mem + 262144);           //   262,144
  float* part   = (float*)(mem + 524288);           //   262,144
  u16*   wslot  = (u16*)(mem + 786432);             // 8,388,608 (JIT bf16 weights)
  u16*   xnorm  = (u16*)(mem + 9175040);            // 4,198,400
  u16*   qr     = (u16*)(mem + 13373440);           // 4,198,400 (qr, later attn)
  u16*   attn   = qr;
  u16*   kr     = (u16*)(mem + 17571840);           // 4,194,304
  char*  big    = mem + 21766144;                   // 16,793,600 (scores|qkvb|hbuf)
  float* scores = (float*)big;
  u16*   qkvb   = (u16*)big;
  u16*   hbuf   = (u16*)big;
  float* x1     = (float*)(mem + 38559744);         // 8,396,800

  // 1. LN1: x -> xnorm (bf16)
  ln_kernel<<<B_ * S_, 256, 0, stream>>>(x, n1w, n1b, xnorm);

  // 2. fused rq|rk GEMM, then l2norm
  conv_kernel<<<1024, 256, 0, stream>>>(rq_w, 0, 1024, wslot, 1 << 20, 10);
  conv_kernel<<<1024, 256, 0, stream>>>(rk_w, 0, 1024, wslot + (1 << 20), 1 << 20, 10);
  mfma_gemm<0><<<dim3(16, 16), 256, 0, stream>>>(xnorm, 1024LL, wslot,
      2048, 2048, 1024, 1024, 1024, (long long)S_ * D_, 0LL,
      rq_b, rk_b, 0, qr, kr, nullptr);
  l2norm_kernel<<<2048, 256, 0, stream>>>(qr);
  l2norm_kernel<<<2048, 256, 0, stream>>>(kr);

  // 3. scores = pos (+diag) then split-K x2 atomic accumulate of qr.kr^T
  init_scores<<<B_ * P_, 256, 0, stream>>>(pos, scores);
  mfma_gemm<5><<<dim3(8, 16, 2), 256, 0, stream>>>(qr, 0LL, kr,
      2048, 1024, 1024, 512, 1024, 1LL << 20, 1LL << 20,
      nullptr, nullptr, 0, nullptr, nullptr, scores);

  // 4. top-32 routing
  topk_kernel<<<512, 256, 0, stream>>>(scores, routes, logw);

  // 5. qkv GEMM (big slot reused)
  conv_kernel<<<3072, 256, 0, stream>>>(qkv_w, 0, 1024, wslot, 3 << 20, 10);
  mfma_gemm<2><<<dim3(24, 17), 256, 0, stream>>>(xnorm, 0LL, wslot,
      2050, 3072, 1024, 1024, 2050, 0LL, 0LL,
      qkv_b, nullptr, 0, qkvb, nullptr, nullptr);

  // 6. attention -> attn (bf16)
  attn_cls_p1<<<dim3(NS_, B_ * H_), 256, 0, stream>>>(qkvb, part);
  attn_cls_p2<<<B_ * H_, 64, 0, stream>>>(part, attn);
  attn_patch_kernel<<<B_ * P_ * H_, 64, 0, stream>>>(qkvb, routes, logw, attn);

  // 7. proj: x1 = x + proj_b, then split-K x2 atomic accumulate
  conv_kernel<<<1024, 256, 0, stream>>>(proj_w, 0, 1024, wslot, 1 << 20, 10);
  init_addb<<<B_ * S_, 256, 0, stream>>>(x, proj_b, x1);
  mfma_gemm<5><<<dim3(8, 17, 2), 256, 0, stream>>>(attn, 0LL, wslot,
      2050, 1024, 1024, 512, 2050, 0LL, 0LL,
      nullptr, nullptr, 0, nullptr, nullptr, x1);

  // 8. LN2: x1 -> xnorm (bf16)
  ln_kernel<<<B_ * S_, 256, 0, stream>>>(x1, n2w, n2b, xnorm);

  // 9. MLP: fc1 -> hbuf (bf16); fc2 split-K x4 atomic into d_out = x1 + fc2_b
  conv_kernel<<<4096, 256, 0, stream>>>(fc1_w, 0, 1024, wslot, 1 << 22, 10);
  mfma_gemm<3><<<dim3(32, 17), 256, 0, stream>>>(xnorm, 0LL, wslot,
      2050, 4096, 1024, 1024, 2050, 0LL, 0LL,
      fc1_b, nullptr, 0, hbuf, nullptr, nullptr);
  conv_kernel<<<4096, 256, 0, stream>>>(fc2_w, 0, 4096, wslot, 1 << 22, 12);
  init_addb<<<B_ * S_, 256, 0, stream>>>(x1, fc2_b, out);
  mfma_gemm<5><<<dim3(8, 17, 4), 256, 0, stream>>>(hbuf, 0LL, wslot,
      2050, 1024, 4096, 1024, 2050, 0LL, 0LL,
      nullptr, nullptr, 0, nullptr, nullptr, out);
}